// Round 1
// baseline (5230.275 us; speedup 1.0000x reference)
//
#include <hip/hip_runtime.h>
#include <cstdint>
#include <cstddef>

// ---------------- problem constants ----------------
static constexpr int TSEQ = 2048;   // T
static constexpr int PSEQ = 256;    // P
static constexpr int DIN  = 300;
static constexpr int NH1  = 600;
static constexpr int NH2  = 2048;

// ---------------- ws layout (bytes) ----------------
static constexpr size_t OFF_X1   = 0;                                   // [2048][2400] f32
static constexpr size_t SZ_X1    = (size_t)TSEQ * 4 * NH1 * 4;
static constexpr size_t OFF_H    = OFF_X1 + SZ_X1;                      // [2][256][600] f32 (dbl buf)
static constexpr size_t SZ_H     = 2ull * PSEQ * NH1 * 4;
static constexpr size_t OFF_C    = OFF_H + SZ_H;                        // [256][600]
static constexpr size_t SZ_C     = (size_t)PSEQ * NH1 * 4;
static constexpr size_t OFF_EMB  = OFF_C + SZ_C;                        // [256][600]
static constexpr size_t SZ_EMB   = (size_t)PSEQ * NH1 * 4;
static constexpr size_t OFF_EMB2 = OFF_EMB + SZ_EMB;                    // [256][600]
static constexpr size_t SZ_EMB2  = (size_t)PSEQ * NH1 * 4;
static constexpr size_t OFF_X2   = OFF_EMB2 + SZ_EMB2;                  // [256][8192]
static constexpr size_t SZ_X2    = (size_t)PSEQ * 4 * NH2 * 4;
static constexpr size_t OFF_PH   = OFF_X2 + SZ_X2;                      // [256][2048]
static constexpr size_t SZ_PH    = (size_t)PSEQ * NH2 * 4;
static constexpr size_t OFF_S    = OFF_PH + SZ_PH;                      // [256][2048]
static constexpr size_t SZ_S     = (size_t)PSEQ * NH2 * 4;
static constexpr size_t OFF_H2   = OFF_S + SZ_S;                        // [2][2048] f32
static constexpr size_t SZ_H2    = 2ull * NH2 * 4;
static constexpr size_t OFF_SSUM = OFF_H2 + SZ_H2;                      // 2048 f32
static constexpr size_t OFF_TMP  = OFF_SSUM + 8192;                     // 2048 f32
static constexpr size_t OFF_META = OFF_TMP + 8192;                      // ints: st[256] L[256] order[256] Ls[256] lmax
static constexpr size_t OFF_SYNC = OFF_META + 8192;                     // barrier counters
static constexpr size_t SZ_SYNC  = 16384;

static constexpr int S1_LDS = (24*612 + 16*612 + 16*24) * 4 + (256 + 256 + 48) * 4;
static constexpr int S2_LDS = 32*2048*2 + (2048 + 32 + 8) * 4;

#define DEVI __device__ __forceinline__

DEVI float sigm(float x) {
    x = fminf(30.f, fmaxf(-30.f, x));
    return 1.f / (1.f + __expf(-x));
}
DEVI float tanh_f(float x) {
    x = fminf(15.f, fmaxf(-15.f, x));
    float t = __expf(2.f * x);
    return (t - 1.f) / (t + 1.f);
}
DEVI uint16_t f2bf(float f) {  // RNE fp32->bf16 (no NaN inputs here)
    uint32_t u = __float_as_uint(f);
    return (uint16_t)((u + 0x7fffu + ((u >> 16) & 1u)) >> 16);
}

// 2-level device-scope barrier; monotonic counters, memset to 0 each launch.
// base layout (ints): bucket b at [b*64], root at [nb*64].
DEVI void grp_barrier(int* base, int bucket, int nb, int pb, int phase) {
    __syncthreads();
    if (threadIdx.x == 0) {
        __threadfence();  // release our h writes
        int old = __hip_atomic_fetch_add(&base[bucket * 64], 1,
                                         __ATOMIC_RELAXED, __HIP_MEMORY_SCOPE_AGENT);
        if ((old % pb) == pb - 1)
            __hip_atomic_fetch_add(&base[nb * 64], 1,
                                   __ATOMIC_RELAXED, __HIP_MEMORY_SCOPE_AGENT);
        const int tgt = nb * (phase + 1);
        while (__hip_atomic_load(&base[nb * 64],
                                 __ATOMIC_RELAXED, __HIP_MEMORY_SCOPE_AGENT) < tgt)
            __builtin_amdgcn_s_sleep(2);
        __threadfence();  // acquire others' h writes
    }
    __syncthreads();
}

// ---------------- generic fp32 GEMM: out[t][r] = act(X[t]·W[r] + bA[r] (+ bB[r])) ----------------
// grid (ceil(R/256), ceil(T/TBLK)), block 256. X-tile broadcast from LDS.
template <int TBLK>
__global__ void __launch_bounds__(256) gemm_rows(
    const float* __restrict__ X, int T, int K,
    const float* __restrict__ W, int R,
    const float* __restrict__ bA, const float* __restrict__ bB,
    float* __restrict__ out, int act)
{
    __shared__ float xt[TBLK][448];
    const int r  = blockIdx.x * 256 + threadIdx.x;
    const int t0 = blockIdx.y * TBLK;
    float acc[TBLK];
#pragma unroll
    for (int i = 0; i < TBLK; ++i) acc[i] = 0.f;

    for (int kc0 = 0; kc0 < K; kc0 += 448) {
        const int kc  = (K - kc0 < 448) ? (K - kc0) : 448;
        const int kc4 = kc >> 2;
        __syncthreads();
        for (int idx = threadIdx.x; idx < TBLK * kc4; idx += 256) {
            int tt = idx / kc4, kk = idx - tt * kc4;
            float4 v = make_float4(0.f, 0.f, 0.f, 0.f);
            if (t0 + tt < T)
                v = *(const float4*)(X + (size_t)(t0 + tt) * K + kc0 + kk * 4);
            *(float4*)(&xt[tt][kk * 4]) = v;
        }
        __syncthreads();
        if (r < R) {
            const float4* wr = (const float4*)(W + (size_t)r * K + kc0);
            for (int k4 = 0; k4 < kc4; ++k4) {
                float4 w4 = wr[k4];
#pragma unroll
                for (int tt = 0; tt < TBLK; ++tt) {
                    float4 x4 = *(const float4*)(&xt[tt][k4 * 4]);
                    acc[tt] = fmaf(w4.x, x4.x, acc[tt]);
                    acc[tt] = fmaf(w4.y, x4.y, acc[tt]);
                    acc[tt] = fmaf(w4.z, x4.z, acc[tt]);
                    acc[tt] = fmaf(w4.w, x4.w, acc[tt]);
                }
            }
        }
    }
    if (r < R) {
        float bb = bA[r] + (bB ? bB[r] : 0.f);
#pragma unroll
        for (int tt = 0; tt < TBLK; ++tt) {
            if (t0 + tt < T) {
                float v = acc[tt] + bb;
                if (act) v = tanh_f(v);
                out[(size_t)(t0 + tt) * R + r] = v;
            }
        }
    }
}

// ---------------- segment starts + length-sort (1 block, 256 threads) ----------------
// meta: [0..256) st, [256..512) L, [512..768) order(sorted idx->p), [768..1024) Ls desc, [1024] lmax
__global__ void __launch_bounds__(256) k_start(
    const float* __restrict__ action, const int* __restrict__ apos, int* __restrict__ meta)
{
    __shared__ int Lsh[256];
    const int p = threadIdx.x;
    const int pos = apos[p];
    int u = pos;
    while (u > 0 && action[u - 1] == 0.0f) --u;   // last reset before pos
    const int L = pos - u + 1;
    meta[p] = u;
    meta[256 + p] = L;
    Lsh[p] = L;
    __syncthreads();
    int rank = 0;
    for (int q = 0; q < 256; ++q) {
        int Lq = Lsh[q];
        if (Lq > L || (Lq == L && q < p)) ++rank;
    }
    meta[512 + rank] = p;
    meta[768 + rank] = L;
    if (rank == 0) meta[1024] = L;
}

// ---------------- stage-1 LSTM: 256 independent chains, lockstep, LDS fp32 weights ----------------
// grid 200 = 100 gate-slices (6 hidden units each) x 2 chain-slices; block 512.
__global__ void __launch_bounds__(512) k_s1(
    const float* __restrict__ X1, const float* __restrict__ Whh1,
    const int* __restrict__ meta,
    float* __restrict__ Hb, float* __restrict__ Cb, float* __restrict__ EMB,
    int* __restrict__ sync)
{
    extern __shared__ char smem[];
    float* wl = (float*)smem;          // [24][612] fp32 weights
    float* hl = wl + 24 * 612;         // [16][612] staged h
    float* gl = hl + 16 * 612;         // [16][24] gate sums
    int* Ls   = (int*)(gl + 16 * 24);  // 256 sorted lengths
    int* ord  = Ls + 256;              // 256 sorted order
    int* chv  = ord + 256;             // 16 chunk chain ids
    int* stv  = chv + 16;              // 16 chunk starts
    int* lnv  = stv + 16;              // 16 chunk lengths

    const int gs = blockIdx.x >> 1;    // gate slice 0..99
    const int cs = blockIdx.x & 1;     // chain slice
    int* syncg = sync + cs * 1024;

    for (int idx = threadIdx.x; idx < 24 * 600; idx += 512) {
        int rr = idx / 600, kk = idx - rr * 600;
        int gamma = rr / 6, u = rr - gamma * 6;
        wl[rr * 612 + kk] = Whh1[(size_t)(gamma * 600 + gs * 6 + u) * 600 + kk];
    }
    for (int idx = threadIdx.x; idx < 256; idx += 512) {
        ord[idx] = meta[512 + idx];
        Ls[idx]  = meta[768 + idx];
    }
    __syncthreads();
    const int lmax = meta[1024];
    int A = 256;  // active chain count (sorted prefix)

    for (int k = 0; k < lmax; ++k) {
        while (A > 0 && Ls[A - 1] <= k) --A;
        const int nj = (A > cs) ? ((A - cs + 1) >> 1) : 0;   // my slice's active count
        const int rb = k & 1;
        const float* Hr = Hb + (size_t)rb * PSEQ * NH1;
        float*       Hw = Hb + (size_t)(rb ^ 1) * PSEQ * NH1;

        for (int c0 = 0; c0 < nj; c0 += 16) {
            const int nc = (nj - c0 < 16) ? (nj - c0) : 16;
            __syncthreads();
            if (threadIdx.x < nc) {
                int i  = cs + 2 * (c0 + threadIdx.x);
                int ch = ord[i];
                chv[threadIdx.x] = ch;
                stv[threadIdx.x] = meta[ch];
                lnv[threadIdx.x] = meta[256 + ch];
            }
            __syncthreads();
            for (int idx = threadIdx.x; idx < nc * 600; idx += 512) {
                int ci = idx / 600, kk = idx - ci * 600;
                hl[ci * 612 + kk] = Hr[(size_t)chv[ci] * NH1 + kk];
            }
            __syncthreads();
            {
                const int tt = threadIdx.x;
                if (tt < 384) {
                    const int rr = tt >> 4, ci = tt & 15;
                    if (ci < nc) {
                        const float4* wr = (const float4*)(wl + rr * 612);
                        const float4* hr = (const float4*)(hl + ci * 612);
                        float a0 = 0, a1 = 0, a2 = 0, a3 = 0;
                        for (int k4 = 0; k4 < 150; ++k4) {
                            float4 w4 = wr[k4], h4 = hr[k4];
                            a0 = fmaf(w4.x, h4.x, a0);
                            a1 = fmaf(w4.y, h4.y, a1);
                            a2 = fmaf(w4.z, h4.z, a2);
                            a3 = fmaf(w4.w, h4.w, a3);
                        }
                        int gamma = rr / 6, u = rr - gamma * 6;
                        int t = stv[ci] + k;
                        float xw = X1[(size_t)t * (4 * NH1) + gamma * 600 + gs * 6 + u];
                        gl[ci * 24 + rr] = (a0 + a1) + (a2 + a3) + xw;
                    }
                }
            }
            __syncthreads();
            if (threadIdx.x < 96) {
                const int ci = threadIdx.x / 6, u = threadIdx.x - ci * 6;
                if (ci < nc) {
                    int ch = chv[ci];
                    float gi = gl[ci * 24 + 0  + u];
                    float gf = gl[ci * 24 + 6  + u];
                    float gg = gl[ci * 24 + 12 + u];
                    float go = gl[ci * 24 + 18 + u];
                    size_t cidx = (size_t)ch * NH1 + gs * 6 + u;
                    float cn = sigm(gf) * Cb[cidx] + sigm(gi) * tanh_f(gg);
                    float hn = sigm(go) * tanh_f(cn);
                    Cb[cidx] = cn;
                    Hw[cidx] = hn;
                    if (k == lnv[ci] - 1) EMB[cidx] = hn;   // chain output at its position
                }
            }
        }
        grp_barrier(syncg, gs % 10, 10, 10, k);
    }
}

// ---------------- stage-2 LSTM: 256 sequential steps, 256 wgs x 8 hidden units ----------------
// Whh2 slice bf16-resident in LDS (131KB); h fp32 double-buffered in global; barrier/step.
__global__ void __launch_bounds__(1024) k_s2(
    const float* __restrict__ X2, const float* __restrict__ Whh2,
    float* __restrict__ h2, float* __restrict__ PH, int* __restrict__ sync)
{
    extern __shared__ char smem[];
    uint16_t* wl  = (uint16_t*)smem;                    // [32][2048] bf16
    float* hlds   = (float*)(smem + 32 * 2048 * 2);     // [2048] fp32
    float* gl     = hlds + 2048;                        // [32]
    float* cl     = gl + 32;                            // [8]
    const int wg  = blockIdx.x;                         // owns units wg*8..wg*8+7
    int* syncg = sync + 2048;

    for (int idx = threadIdx.x; idx < 32 * 512; idx += 1024) {
        int rr = idx >> 9, k4 = idx & 511;
        int gamma = rr >> 3, u = rr & 7;
        float4 v = *(const float4*)(Whh2 + (size_t)(gamma * NH2 + wg * 8 + u) * NH2 + k4 * 4);
        uint32_t p0 = (uint32_t)f2bf(v.x) | ((uint32_t)f2bf(v.y) << 16);
        uint32_t p1 = (uint32_t)f2bf(v.z) | ((uint32_t)f2bf(v.w) << 16);
        uint32_t* dst = (uint32_t*)(wl + rr * 2048 + k4 * 4);
        dst[0] = p0; dst[1] = p1;
    }
    if (threadIdx.x < 8) cl[threadIdx.x] = 0.f;
    __syncthreads();

    const int g    = threadIdx.x >> 6;   // 0..15 -> rows g and g+16
    const int lane = threadIdx.x & 63;

    for (int t = 0; t < PSEQ; ++t) {
        const int rb = t & 1;
        {   // stage h (2048 f32) to LDS
            float2 hv = *(const float2*)(h2 + rb * NH2 + threadIdx.x * 2);
            *(float2*)(hlds + threadIdx.x * 2) = hv;
        }
        __syncthreads();
        float acc0 = 0.f, acc1 = 0.f;
#pragma unroll
        for (int j = 0; j < 16; ++j) {
            int kk = lane * 2 + j * 128;
            float2 hv = *(const float2*)(hlds + kk);
            uint32_t w0 = *(const uint32_t*)(wl + (size_t)g * 2048 + kk);
            uint32_t w1 = *(const uint32_t*)(wl + (size_t)(g + 16) * 2048 + kk);
            acc0 = fmaf(__uint_as_float(w0 << 16),          hv.x, acc0);
            acc0 = fmaf(__uint_as_float(w0 & 0xffff0000u),  hv.y, acc0);
            acc1 = fmaf(__uint_as_float(w1 << 16),          hv.x, acc1);
            acc1 = fmaf(__uint_as_float(w1 & 0xffff0000u),  hv.y, acc1);
        }
#pragma unroll
        for (int m = 32; m > 0; m >>= 1) {
            acc0 += __shfl_xor(acc0, m, 64);
            acc1 += __shfl_xor(acc1, m, 64);
        }
        if (lane == 0) { gl[g] = acc0; gl[g + 16] = acc1; }
        __syncthreads();
        if (threadIdx.x < 8) {
            int u = threadIdx.x, uu = wg * 8 + u;
            const float* xr = X2 + (size_t)t * (4 * NH2);
            float gi = gl[u]      + xr[0 * NH2 + uu];
            float gf = gl[8 + u]  + xr[1 * NH2 + uu];
            float gg = gl[16 + u] + xr[2 * NH2 + uu];
            float go = gl[24 + u] + xr[3 * NH2 + uu];
            float cn = sigm(gf) * cl[u] + sigm(gi) * tanh_f(gg);
            float hn = sigm(go) * tanh_f(cn);
            cl[u] = cn;
            h2[(rb ^ 1) * NH2 + uu] = hn;
            PH[(size_t)t * NH2 + uu] = hn;
        }
        grp_barrier(syncg, wg & 15, 16, 16, t);
    }
}

// ---------------- column sum of S -> SSUM ----------------
__global__ void __launch_bounds__(256) k_colsum(const float* __restrict__ S, float* __restrict__ out)
{
    const int j = blockIdx.x * 256 + threadIdx.x;
    float a = 0.f;
    for (int t = 0; t < PSEQ; ++t) a += S[(size_t)t * NH2 + j];
    out[j] = a;
}

// ---------------- matvec: vout[r] = W[r]·vin + bscale*b[r] ----------------
__global__ void __launch_bounds__(256) k_mv(
    const float* __restrict__ W, const float* __restrict__ b, float bscale,
    const float* __restrict__ vin, float* __restrict__ vout)
{
    __shared__ float v[NH2];
    for (int i = threadIdx.x; i < NH2; i += 256) v[i] = vin[i];
    __syncthreads();
    const int r = blockIdx.x * 256 + threadIdx.x;
    const float4* wr = (const float4*)(W + (size_t)r * NH2);
    float a0 = 0, a1 = 0, a2 = 0, a3 = 0;
    for (int k4 = 0; k4 < NH2 / 4; ++k4) {
        float4 w4 = wr[k4];
        float4 x4 = *(const float4*)(&v[k4 * 4]);
        a0 = fmaf(w4.x, x4.x, a0); a1 = fmaf(w4.y, x4.y, a1);
        a2 = fmaf(w4.z, x4.z, a2); a3 = fmaf(w4.w, x4.w, a3);
    }
    vout[r] = (a0 + a1) + (a2 + a3) + bscale * b[r];
}

extern "C" void kernel_launch(void* const* d_in, const int* in_sizes, int n_in,
                              void* d_out, int out_size, void* d_ws, size_t ws_size,
                              hipStream_t stream)
{
    const float* sent   = (const float*)d_in[0];
    const float* action = (const float*)d_in[1];
    const int*   apos   = (const int*)  d_in[2];
    const float* Wih1   = (const float*)d_in[3];
    const float* Whh1   = (const float*)d_in[4];
    const float* bih1   = (const float*)d_in[5];
    const float* bhh1   = (const float*)d_in[6];
    const float* W1     = (const float*)d_in[7];
    const float* b1     = (const float*)d_in[8];
    const float* Wih2   = (const float*)d_in[9];
    const float* Whh2   = (const float*)d_in[10];
    const float* bih2   = (const float*)d_in[11];
    const float* bhh2   = (const float*)d_in[12];
    const float* W2     = (const float*)d_in[13];
    const float* b2     = (const float*)d_in[14];
    const float* ipw    = (const float*)d_in[15];
    const float* ipb    = (const float*)d_in[16];
    const float* opw    = (const float*)d_in[17];
    const float* opb    = (const float*)d_in[18];

    char* ws = (char*)d_ws;
    float* X1   = (float*)(ws + OFF_X1);
    float* Hb   = (float*)(ws + OFF_H);
    float* Cb   = (float*)(ws + OFF_C);
    float* EMB  = (float*)(ws + OFF_EMB);
    float* EMB2 = (float*)(ws + OFF_EMB2);
    float* X2   = (float*)(ws + OFF_X2);
    float* PH   = (float*)(ws + OFF_PH);
    float* S    = (float*)(ws + OFF_S);
    float* H2   = (float*)(ws + OFF_H2);
    float* SSUM = (float*)(ws + OFF_SSUM);
    float* TMP  = (float*)(ws + OFF_TMP);
    int*   META = (int*)  (ws + OFF_META);
    int*   SYNC = (int*)  (ws + OFF_SYNC);

    // re-zero stateful buffers every call (graph replays)
    hipMemsetAsync(ws + OFF_H, 0, SZ_H + SZ_C, stream);
    hipMemsetAsync(ws + OFF_H2, 0, (OFF_SYNC + SZ_SYNC) - OFF_H2, stream);

    hipFuncSetAttribute((const void*)k_s1, hipFuncAttributeMaxDynamicSharedMemorySize, S1_LDS);
    hipFuncSetAttribute((const void*)k_s2, hipFuncAttributeMaxDynamicSharedMemorySize, S2_LDS);

    // X1 = sent @ Wih1.T + bih1 + bhh1   (2048 x 2400, K=300)
    gemm_rows<32><<<dim3(10, 64), 256, 0, stream>>>(sent, TSEQ, DIN, Wih1, 4 * NH1, bih1, bhh1, X1, 0);
    // segment starts / lengths / sort
    k_start<<<1, 256, 0, stream>>>(action, apos, META);
    // stage-1 chains -> EMB (h at each gathered position)
    k_s1<<<200, 512, S1_LDS, stream>>>(X1, Whh1, META, Hb, Cb, EMB, SYNC);
    // EMB2 = tanh(EMB @ W1.T + b1)       (256 x 600, K=600)
    gemm_rows<8><<<dim3(3, 32), 256, 0, stream>>>(EMB, PSEQ, NH1, W1, NH1, b1, nullptr, EMB2, 1);
    // X2 = EMB2 @ Wih2.T + bih2 + bhh2   (256 x 8192, K=600)
    gemm_rows<32><<<dim3(32, 8), 256, 0, stream>>>(EMB2, PSEQ, NH1, Wih2, 4 * NH2, bih2, bhh2, X2, 0);
    // stage-2 LSTM -> PH (256 x 2048)
    k_s2<<<256, 1024, S2_LDS, stream>>>(X2, Whh2, H2, PH, SYNC);
    // S = tanh(PH @ W2.T + b2)           (256 x 2048, K=2048)
    gemm_rows<8><<<dim3(8, 32), 256, 0, stream>>>(PH, PSEQ, NH2, W2, NH2, b2, nullptr, S, 1);
    // SSUM = column sums of S
    k_colsum<<<8, 256, 0, stream>>>(S, SSUM);
    // attention collapse: out = (SSUM @ Wv.T + 256*bv) @ Wo.T + 256*bo
    k_mv<<<8, 256, 0, stream>>>(ipw + (size_t)4096 * NH2, ipb + 4096, 256.f, SSUM, TMP);
    k_mv<<<8, 256, 0, stream>>>(opw, opb, 256.f, TMP, (float*)d_out);
}

// Round 2
// 3556.133 us; speedup vs baseline: 1.4708x; 1.4708x over previous
//
#include <hip/hip_runtime.h>
#include <cstdint>
#include <cstddef>

// ---------------- problem constants ----------------
static constexpr int TSEQ = 2048;   // T
static constexpr int PSEQ = 256;    // P
static constexpr int DIN  = 300;
static constexpr int NH1  = 600;
static constexpr int NH2  = 2048;

// ---------------- ws layout (bytes) ----------------
static constexpr size_t OFF_X1   = 0;                                   // [2048][2400] f32
static constexpr size_t SZ_X1    = (size_t)TSEQ * 4 * NH1 * 4;
static constexpr size_t OFF_HBF  = OFF_X1 + SZ_X1;                      // [2][256][600] bf16 dbl-buf
static constexpr size_t SZ_HBF   = 2ull * PSEQ * NH1 * 2;
static constexpr size_t OFF_EMB  = OFF_HBF + SZ_HBF;                    // [256][600] f32
static constexpr size_t SZ_EMB   = (size_t)PSEQ * NH1 * 4;
static constexpr size_t OFF_EMB2 = OFF_EMB + SZ_EMB;                    // [256][600] f32
static constexpr size_t SZ_EMB2  = (size_t)PSEQ * NH1 * 4;
static constexpr size_t OFF_X2   = OFF_EMB2 + SZ_EMB2;                  // [256][8192] f32
static constexpr size_t SZ_X2    = (size_t)PSEQ * 4 * NH2 * 4;
static constexpr size_t OFF_PH   = OFF_X2 + SZ_X2;                      // [256][2048] f32
static constexpr size_t SZ_PH    = (size_t)PSEQ * NH2 * 4;
static constexpr size_t OFF_S    = OFF_PH + SZ_PH;                      // [256][2048] f32
static constexpr size_t SZ_S     = (size_t)PSEQ * NH2 * 4;
static constexpr size_t OFF_H2   = OFF_S + SZ_S;                        // [2][2048] f32
static constexpr size_t SZ_H2    = 2ull * NH2 * 4;
static constexpr size_t OFF_SSUM = OFF_H2 + SZ_H2;                      // 2048 f32
static constexpr size_t OFF_TMP  = OFF_SSUM + 8192;                     // 2048 f32
static constexpr size_t OFF_META = OFF_TMP + 8192;                      // ints: st[256] L[256] ord[256] Ls[256] lmax
static constexpr size_t OFF_SYNC = OFF_META + 8192;                     // barrier counters (2 regions x 2048 ints)
static constexpr size_t SZ_SYNC  = 16384;

// k_s1 dynamic LDS: W 32x600 bf16 + h 64x600 bf16 + g 32x68 f32 + c 256x8 f32 + meta 3x256 int
static constexpr int S1_LDS = (32*600 + 64*600) * 2 + 32*68*4 + 256*8*4 + 3*256*4;   // 135168

#define DEVI __device__ __forceinline__

typedef __attribute__((ext_vector_type(8))) short short8v;   // 8 bf16 (4 VGPRs)
typedef __attribute__((ext_vector_type(4))) float f32x4;     // MFMA acc

DEVI float sigm(float x) {
    x = fminf(30.f, fmaxf(-30.f, x));
    return 1.f / (1.f + __expf(-x));
}
DEVI float tanh_f(float x) {
    x = fminf(15.f, fmaxf(-15.f, x));
    float t = __expf(2.f * x);
    return (t - 1.f) / (t + 1.f);
}
DEVI uint16_t f2bf(float f) {  // RNE fp32->bf16
    uint32_t u = __float_as_uint(f);
    return (uint16_t)((u + 0x7fffu + ((u >> 16) & 1u)) >> 16);
}

// ---- hierarchical device barrier v2: bucket arrive -> root -> per-bucket go flags ----
// area layout (ints): arrive[b] @ b*32 ; root @ 600 ; go[b] @ 1024 + b*32.
// <=16 spinners per go-line (vs 240 on one root line in v1) — kills spin contention.
DEVI void barrier2(int* area, int wgid, int nb, int pb, int phase) {
    __syncthreads();   // emits per-wave vmcnt(0): all waves' global stores are in L2
    if (threadIdx.x == 0) {
        __threadfence();   // agent release: flush so h-writes visible device-wide
        const int b = wgid % nb;
        int old = __hip_atomic_fetch_add(&area[b * 32], 1,
                                         __ATOMIC_RELAXED, __HIP_MEMORY_SCOPE_AGENT);
        if ((old % pb) == pb - 1) {
            int old2 = __hip_atomic_fetch_add(&area[600], 1,
                                              __ATOMIC_RELAXED, __HIP_MEMORY_SCOPE_AGENT);
            if ((old2 % nb) == nb - 1) {           // last arriver overall -> releaser
                for (int i = 0; i < nb; ++i)
                    __hip_atomic_store(&area[1024 + i * 32], phase + 1,
                                       __ATOMIC_RELAXED, __HIP_MEMORY_SCOPE_AGENT);
            }
        }
        while (__hip_atomic_load(&area[1024 + b * 32],
                                 __ATOMIC_RELAXED, __HIP_MEMORY_SCOPE_AGENT) < phase + 1)
            __builtin_amdgcn_s_sleep(2);
        __threadfence();   // agent acquire: invalidate L1/L2 so h-reads are fresh
    }
    __syncthreads();
}

// ---------------- generic fp32 GEMM: out[t][r] = act(X[t]·W[r] + bA[r] (+ bB[r])) ----------------
template <int TBLK>
__global__ void __launch_bounds__(256) gemm_rows(
    const float* __restrict__ X, int T, int K,
    const float* __restrict__ W, int R,
    const float* __restrict__ bA, const float* __restrict__ bB,
    float* __restrict__ out, int act)
{
    __shared__ float xt[TBLK][448];
    const int r  = blockIdx.x * 256 + threadIdx.x;
    const int t0 = blockIdx.y * TBLK;
    float acc[TBLK];
#pragma unroll
    for (int i = 0; i < TBLK; ++i) acc[i] = 0.f;

    for (int kc0 = 0; kc0 < K; kc0 += 448) {
        const int kc  = (K - kc0 < 448) ? (K - kc0) : 448;
        const int kc4 = kc >> 2;
        __syncthreads();
        for (int idx = threadIdx.x; idx < TBLK * kc4; idx += 256) {
            int tt = idx / kc4, kk = idx - tt * kc4;
            float4 v = make_float4(0.f, 0.f, 0.f, 0.f);
            if (t0 + tt < T)
                v = *(const float4*)(X + (size_t)(t0 + tt) * K + kc0 + kk * 4);
            *(float4*)(&xt[tt][kk * 4]) = v;
        }
        __syncthreads();
        if (r < R) {
            const float4* wr = (const float4*)(W + (size_t)r * K + kc0);
            for (int k4 = 0; k4 < kc4; ++k4) {
                float4 w4 = wr[k4];
#pragma unroll
                for (int tt = 0; tt < TBLK; ++tt) {
                    float4 x4 = *(const float4*)(&xt[tt][k4 * 4]);
                    acc[tt] = fmaf(w4.x, x4.x, acc[tt]);
                    acc[tt] = fmaf(w4.y, x4.y, acc[tt]);
                    acc[tt] = fmaf(w4.z, x4.z, acc[tt]);
                    acc[tt] = fmaf(w4.w, x4.w, acc[tt]);
                }
            }
        }
    }
    if (r < R) {
        float bb = bA[r] + (bB ? bB[r] : 0.f);
#pragma unroll
        for (int tt = 0; tt < TBLK; ++tt) {
            if (t0 + tt < T) {
                float v = acc[tt] + bb;
                if (act) v = tanh_f(v);
                out[(size_t)(t0 + tt) * R + r] = v;
            }
        }
    }
}

// ---------------- segment starts + length-sort (1 block, 256 threads) ----------------
__global__ void __launch_bounds__(256) k_start(
    const float* __restrict__ action, const int* __restrict__ apos, int* __restrict__ meta)
{
    __shared__ int Lsh[256];
    const int p = threadIdx.x;
    const int pos = apos[p];
    int u = pos;
    while (u > 0 && action[u - 1] == 0.0f) --u;
    const int L = pos - u + 1;
    meta[p] = u;
    meta[256 + p] = L;
    Lsh[p] = L;
    __syncthreads();
    int rank = 0;
    for (int q = 0; q < 256; ++q) {
        int Lq = Lsh[q];
        if (Lq > L || (Lq == L && q < p)) ++rank;
    }
    meta[512 + rank] = p;
    meta[768 + rank] = L;
    if (rank == 0) meta[1024] = L;
}

// ---------------- stage-1 LSTM via MFMA: 75 wgs x 8 units, chains lockstep ----------------
// Per step: gates[chain][row] = h_bf16 · Whh1_bf16^T via mfma_f32_16x16x32_bf16.
// A-frag (h):   lane l -> chain = ct*16 + (l&15),   k = kt*32 + (l>>4)*8 + i
// B-frag (W^T): lane l -> row   = rt*16 + (l&15),   k = same      (B[k][n] = W[n][k])
// C/D:          lane l -> chain m = ct*16 + (l>>4)*4 + reg, row n = rt*16 + (l&15)  [m89]
__global__ void __launch_bounds__(512) k_s1(
    const float* __restrict__ X1, const float* __restrict__ Whh1,
    const int* __restrict__ meta,
    unsigned short* __restrict__ Hbf, float* __restrict__ EMB,
    int* __restrict__ sync)
{
    extern __shared__ char smem[];
    unsigned short* wl = (unsigned short*)smem;            // [32][600] bf16, stride 1200B (2-way banks: free)
    unsigned short* hl = wl + 32 * 600;                    // [64][600] bf16
    float* glds = (float*)(hl + 64 * 600);                 // [32][68] gates
    float* clds = glds + 32 * 68;                          // [256][8] c-state (global chain id)
    int* ordC  = (int*)(clds + 256 * 8);                   // 256 sorted chain ids
    int* ordST = ordC + 256;
    int* ordL  = ordST + 256;

    const int wg  = blockIdx.x;        // 0..74, owns units u0..u0+7
    const int u0  = wg * 8;
    const int tid = threadIdx.x;
    const int lane = tid & 63;
    const int w  = tid >> 6;           // wave 0..7
    const int ct = w & 3, rt = w >> 2; // chain-tile, row-tile

    // stage weights (rows ordered gamma*8+u), convert to bf16
    for (int idx = tid; idx < 32 * 150; idx += 512) {
        int rr = idx / 150, j = idx - rr * 150;
        int gamma = rr >> 3, u = rr & 7;
        float4 v = *(const float4*)(Whh1 + (size_t)(gamma * 600 + u0 + u) * 600 + j * 4);
        ushort4 pk = make_ushort4(f2bf(v.x), f2bf(v.y), f2bf(v.z), f2bf(v.w));
        *(ushort4*)(wl + rr * 600 + j * 4) = pk;
    }
    if (tid < 256) {
        int p = meta[512 + tid];
        ordC[tid]  = p;
        ordST[tid] = meta[p];
        ordL[tid]  = meta[256 + p];
    }
    for (int idx = tid; idx < 2048; idx += 512) clds[idx] = 0.f;
    __syncthreads();

    const int lmax = ordL[0];
    int A = 256;

    for (int k = 0; k < lmax; ++k) {
        while (A > 0 && ordL[A - 1] <= k) --A;
        const int rb = k & 1;
        const unsigned short* Hr = Hbf + (size_t)rb * PSEQ * NH1;
        unsigned short*       Hw = Hbf + (size_t)(rb ^ 1) * PSEQ * NH1;
        const int ng = (A + 63) >> 6;

        for (int g = 0; g < ng; ++g) {
            const int sc  = (A - g * 64 < 64) ? (A - g * 64) : 64;
            const int nst = (sc + 15) & ~15;
            // stage h (bf16) for nst slots
            for (int idx = tid; idx < nst * 75; idx += 512) {
                int ci = idx / 75, j = idx - ci * 75;
                int ch = ordC[g * 64 + ci];
                *(uint4*)(hl + ci * 600 + j * 8) =
                    *(const uint4*)(Hr + (size_t)ch * 600 + j * 8);
            }
            __syncthreads();

            // epilogue-role prefetch (independent of h): X1 gate values + meta
            const int s_loc = tid >> 3, eu = tid & 7;
            const bool ep = (s_loc < sc);
            int ch = 0, st = 0, L = 0;
            float xv0 = 0, xv1 = 0, xv2 = 0, xv3 = 0;
            if (ep) {
                ch = ordC[g * 64 + s_loc];
                st = ordST[g * 64 + s_loc];
                L  = ordL[g * 64 + s_loc];
                const float* xr = X1 + (size_t)(st + k) * 2400 + u0 + eu;
                xv0 = xr[0]; xv1 = xr[600]; xv2 = xr[1200]; xv3 = xr[1800];
            }

            // MFMA: D[chain][row] += h · W^T
            if (ct * 16 < sc) {
                f32x4 acc = {0.f, 0.f, 0.f, 0.f};
                const int kg = lane >> 4;
                const short* ha = (const short*)hl + (ct * 16 + (lane & 15)) * 600;
                const short* wb = (const short*)wl + (rt * 16 + (lane & 15)) * 600;
#pragma unroll
                for (int kt = 0; kt < 19; ++kt) {
                    int k0 = kt * 32 + kg * 8;
                    short8v af = {0, 0, 0, 0, 0, 0, 0, 0};
                    short8v bf = {0, 0, 0, 0, 0, 0, 0, 0};
                    if (k0 < 600) {
                        af = *(const short8v*)(ha + k0);
                        bf = *(const short8v*)(wb + k0);
                    }
                    acc = __builtin_amdgcn_mfma_f32_16x16x32_bf16(af, bf, acc, 0, 0, 0);
                }
                const int brow = rt * 16 + (lane & 15);
                const int ch0  = ct * 16 + ((lane >> 4) << 2);
                *(f32x4*)(glds + brow * 68 + ch0) = acc;
            }
            __syncthreads();

            // gate epilogue: thread (s_loc, eu) owns (chain slot, unit)
            if (ep) {
                float gi = glds[(0 * 8 + eu) * 68 + s_loc] + xv0;
                float gf = glds[(1 * 8 + eu) * 68 + s_loc] + xv1;
                float gg = glds[(2 * 8 + eu) * 68 + s_loc] + xv2;
                float go = glds[(3 * 8 + eu) * 68 + s_loc] + xv3;
                float co = clds[ch * 8 + eu];
                float cn = sigm(gf) * co + sigm(gi) * tanh_f(gg);
                float hn = sigm(go) * tanh_f(cn);
                clds[ch * 8 + eu] = cn;
                Hw[(size_t)ch * 600 + u0 + eu] = f2bf(hn);
                if (k == L - 1) EMB[(size_t)ch * 600 + u0 + eu] = hn;
            }
        }
        if (k < lmax - 1) barrier2(sync, wg, 15, 5, k);   // 75 = 15 buckets x 5
    }
}

// ---------------- stage-2 LSTM: 256 wgs x 8 units; Whh2 fp32 resident in VGPRs ----------------
__global__ void __launch_bounds__(1024) k_s2(
    const float* __restrict__ X2, const float* __restrict__ Whh2,
    float* __restrict__ h2, float* __restrict__ PH, int* __restrict__ sync)
{
    __shared__ float gl[32];
    __shared__ float cl[8];
    const int wg   = blockIdx.x;
    const int tid  = threadIdx.x;
    const int lane = tid & 63;
    const int w    = tid >> 6;        // 0..15: rows w (gammas 0/1) and w+16 (gammas 2/3)
    const int u    = w & 7, gbit = w >> 3;
    const int uu   = wg * 8 + u;
    int* syncg = sync + 2048;         // s2 region

    // preload weights fp32 into VGPRs: k(j,c) = j*256 + lane*4 + c
    float w0[32], w1[32];
    {
        const float* r0 = Whh2 + ((size_t)(gbit * NH2 + uu)) * NH2;
        const float* r1 = Whh2 + ((size_t)((2 + gbit) * NH2 + uu)) * NH2;
#pragma unroll
        for (int j = 0; j < 8; ++j) {
            float4 a = *(const float4*)(r0 + j * 256 + lane * 4);
            float4 b = *(const float4*)(r1 + j * 256 + lane * 4);
            w0[j*4+0] = a.x; w0[j*4+1] = a.y; w0[j*4+2] = a.z; w0[j*4+3] = a.w;
            w1[j*4+0] = b.x; w1[j*4+1] = b.y; w1[j*4+2] = b.z; w1[j*4+3] = b.w;
        }
    }
    if (tid < 8) cl[tid] = 0.f;
    __syncthreads();

    for (int t = 0; t < PSEQ; ++t) {
        const int rb = t & 1;
        // prefetch this step's x-gate values (static input, no dependency)
        float x0 = 0, x1 = 0, x2 = 0, x3 = 0;
        if (tid < 8) {
            const float* xr = X2 + (size_t)t * (4 * NH2) + wg * 8 + tid;
            x0 = xr[0]; x1 = xr[NH2]; x2 = xr[2 * NH2]; x3 = xr[3 * NH2];
        }
        const float* hr = h2 + rb * NH2;
        float acc0 = 0.f, acc1 = 0.f;
#pragma unroll
        for (int j = 0; j < 8; ++j) {
            float4 hv = *(const float4*)(hr + j * 256 + lane * 4);
            acc0 = fmaf(w0[j*4+0], hv.x, acc0); acc1 = fmaf(w1[j*4+0], hv.x, acc1);
            acc0 = fmaf(w0[j*4+1], hv.y, acc0); acc1 = fmaf(w1[j*4+1], hv.y, acc1);
            acc0 = fmaf(w0[j*4+2], hv.z, acc0); acc1 = fmaf(w1[j*4+2], hv.z, acc1);
            acc0 = fmaf(w0[j*4+3], hv.w, acc0); acc1 = fmaf(w1[j*4+3], hv.w, acc1);
        }
#pragma unroll
        for (int m = 32; m > 0; m >>= 1) {
            acc0 += __shfl_xor(acc0, m, 64);
            acc1 += __shfl_xor(acc1, m, 64);
        }
        if (lane == 0) { gl[w] = acc0; gl[w + 16] = acc1; }
        __syncthreads();
        if (tid < 8) {
            float gi = gl[0  + tid] + x0;
            float gf = gl[8  + tid] + x1;
            float gg = gl[16 + tid] + x2;
            float go = gl[24 + tid] + x3;
            float cn = sigm(gf) * cl[tid] + sigm(gi) * tanh_f(gg);
            float hn = sigm(go) * tanh_f(cn);
            cl[tid] = cn;
            h2[(rb ^ 1) * NH2 + wg * 8 + tid] = hn;
            PH[(size_t)t * NH2 + wg * 8 + tid] = hn;
        }
        if (t < PSEQ - 1) barrier2(syncg, wg, 16, 16, t);   // 256 = 16 x 16
    }
}

// ---------------- column sum of S -> SSUM ----------------
__global__ void __launch_bounds__(256) k_colsum(const float* __restrict__ S, float* __restrict__ out)
{
    const int j = blockIdx.x * 256 + threadIdx.x;
    float a = 0.f;
    for (int t = 0; t < PSEQ; ++t) a += S[(size_t)t * NH2 + j];
    out[j] = a;
}

// ---------------- matvec: vout[r] = W[r]·vin + bscale*b[r] ----------------
__global__ void __launch_bounds__(256) k_mv(
    const float* __restrict__ W, const float* __restrict__ b, float bscale,
    const float* __restrict__ vin, float* __restrict__ vout)
{
    __shared__ float v[NH2];
    for (int i = threadIdx.x; i < NH2; i += 256) v[i] = vin[i];
    __syncthreads();
    const int r = blockIdx.x * 256 + threadIdx.x;
    const float4* wr = (const float4*)(W + (size_t)r * NH2);
    float a0 = 0, a1 = 0, a2 = 0, a3 = 0;
    for (int k4 = 0; k4 < NH2 / 4; ++k4) {
        float4 w4 = wr[k4];
        float4 x4 = *(const float4*)(&v[k4 * 4]);
        a0 = fmaf(w4.x, x4.x, a0); a1 = fmaf(w4.y, x4.y, a1);
        a2 = fmaf(w4.z, x4.z, a2); a3 = fmaf(w4.w, x4.w, a3);
    }
    vout[r] = (a0 + a1) + (a2 + a3) + bscale * b[r];
}

extern "C" void kernel_launch(void* const* d_in, const int* in_sizes, int n_in,
                              void* d_out, int out_size, void* d_ws, size_t ws_size,
                              hipStream_t stream)
{
    const float* sent   = (const float*)d_in[0];
    const float* action = (const float*)d_in[1];
    const int*   apos   = (const int*)  d_in[2];
    const float* Wih1   = (const float*)d_in[3];
    const float* Whh1   = (const float*)d_in[4];
    const float* bih1   = (const float*)d_in[5];
    const float* bhh1   = (const float*)d_in[6];
    const float* W1     = (const float*)d_in[7];
    const float* b1     = (const float*)d_in[8];
    const float* Wih2   = (const float*)d_in[9];
    const float* Whh2   = (const float*)d_in[10];
    const float* bih2   = (const float*)d_in[11];
    const float* bhh2   = (const float*)d_in[12];
    const float* W2     = (const float*)d_in[13];
    const float* b2     = (const float*)d_in[14];
    const float* ipw    = (const float*)d_in[15];
    const float* ipb    = (const float*)d_in[16];
    const float* opw    = (const float*)d_in[17];
    const float* opb    = (const float*)d_in[18];

    char* ws = (char*)d_ws;
    float*          X1   = (float*)(ws + OFF_X1);
    unsigned short* HBF  = (unsigned short*)(ws + OFF_HBF);
    float*          EMB  = (float*)(ws + OFF_EMB);
    float*          EMB2 = (float*)(ws + OFF_EMB2);
    float*          X2   = (float*)(ws + OFF_X2);
    float*          PH   = (float*)(ws + OFF_PH);
    float*          S    = (float*)(ws + OFF_S);
    float*          H2   = (float*)(ws + OFF_H2);
    float*          SSUM = (float*)(ws + OFF_SSUM);
    float*          TMP  = (float*)(ws + OFF_TMP);
    int*            META = (int*)  (ws + OFF_META);
    int*            SYNC = (int*)  (ws + OFF_SYNC);

    // re-zero stateful buffers every call (graph replays)
    hipMemsetAsync(ws + OFF_HBF, 0, SZ_HBF, stream);
    hipMemsetAsync(ws + OFF_H2, 0, SZ_H2, stream);
    hipMemsetAsync(ws + OFF_SYNC, 0, SZ_SYNC, stream);

    hipFuncSetAttribute((const void*)k_s1, hipFuncAttributeMaxDynamicSharedMemorySize, S1_LDS);

    // X1 = sent @ Wih1.T + bih1 + bhh1   (2048 x 2400, K=300)
    gemm_rows<32><<<dim3(10, 64), 256, 0, stream>>>(sent, TSEQ, DIN, Wih1, 4 * NH1, bih1, bhh1, X1, 0);
    // segment starts / lengths / sort
    k_start<<<1, 256, 0, stream>>>(action, apos, META);
    // stage-1 chains (MFMA) -> EMB
    k_s1<<<75, 512, S1_LDS, stream>>>(X1, Whh1, META, HBF, EMB, SYNC);
    // EMB2 = tanh(EMB @ W1.T + b1)       (256 x 600, K=600)
    gemm_rows<8><<<dim3(3, 32), 256, 0, stream>>>(EMB, PSEQ, NH1, W1, NH1, b1, nullptr, EMB2, 1);
    // X2 = EMB2 @ Wih2.T + bih2 + bhh2   (256 x 8192, K=600)
    gemm_rows<32><<<dim3(32, 8), 256, 0, stream>>>(EMB2, PSEQ, NH1, Wih2, 4 * NH2, bih2, bhh2, X2, 0);
    // stage-2 LSTM -> PH (256 x 2048)
    k_s2<<<256, 1024, 0, stream>>>(X2, Whh2, H2, PH, SYNC);
    // S = tanh(PH @ W2.T + b2)           (256 x 2048, K=2048)
    gemm_rows<8><<<dim3(8, 32), 256, 0, stream>>>(PH, PSEQ, NH2, W2, NH2, b2, nullptr, S, 1);
    // SSUM = column sums of S
    k_colsum<<<8, 256, 0, stream>>>(S, SSUM);
    // attention collapse: out = (SSUM @ Wv.T + 256*bv) @ Wo.T + 256*bo
    k_mv<<<8, 256, 0, stream>>>(ipw + (size_t)4096 * NH2, ipb + 4096, 256.f, SSUM, TMP);
    k_mv<<<8, 256, 0, stream>>>(opw, opb, 256.f, TMP, (float*)d_out);
}

// Round 3
// 2248.623 us; speedup vs baseline: 2.3260x; 1.5815x over previous
//
#include <hip/hip_runtime.h>
#include <cstdint>
#include <cstddef>

// ---------------- problem constants ----------------
static constexpr int TSEQ = 2048;   // T
static constexpr int PSEQ = 256;    // P
static constexpr int DIN  = 300;
static constexpr int NH1  = 600;
static constexpr int NH2  = 2048;

// ---------------- ws layout (bytes) ----------------
static constexpr size_t OFF_X1   = 0;                                   // [2048][2400] f32
static constexpr size_t SZ_X1    = (size_t)TSEQ * 4 * NH1 * 4;
static constexpr size_t OFF_HBF  = OFF_X1 + SZ_X1;                      // [2][256][600] bf16 dbl-buf
static constexpr size_t SZ_HBF   = 2ull * PSEQ * NH1 * 2;
static constexpr size_t OFF_EMB  = OFF_HBF + SZ_HBF;                    // [256][600] f32
static constexpr size_t SZ_EMB   = (size_t)PSEQ * NH1 * 4;
static constexpr size_t OFF_EMB2 = OFF_EMB + SZ_EMB;                    // [256][600] f32
static constexpr size_t SZ_EMB2  = (size_t)PSEQ * NH1 * 4;
static constexpr size_t OFF_X2   = OFF_EMB2 + SZ_EMB2;                  // [256][8192] f32
static constexpr size_t SZ_X2    = (size_t)PSEQ * 4 * NH2 * 4;
static constexpr size_t OFF_PH   = OFF_X2 + SZ_X2;                      // [256][2048] f32
static constexpr size_t SZ_PH    = (size_t)PSEQ * NH2 * 4;
static constexpr size_t OFF_S    = OFF_PH + SZ_PH;                      // [256][2048] f32
static constexpr size_t SZ_S     = (size_t)PSEQ * NH2 * 4;
static constexpr size_t OFF_H2   = OFF_S + SZ_S;                        // [2][2048] f32
static constexpr size_t SZ_H2    = 2ull * NH2 * 4;
static constexpr size_t OFF_SSUM = OFF_H2 + SZ_H2;                      // 2048 f32
static constexpr size_t OFF_TMP  = OFF_SSUM + 8192;                     // 2048 f32
static constexpr size_t OFF_META = OFF_TMP + 8192;                      // ints: st[256] L[256] ord[256] Ls[256] lmax
static constexpr size_t OFF_SYNC = OFF_META + 8192;                     // barrier counters (2 regions x 2048 ints)
static constexpr size_t SZ_SYNC  = 16384;

// k_s1 dynamic LDS: W 32x600 bf16 + h 64x600 bf16 + g 32x68 f32 + c 256x8 f32 + meta 3x256 int
static constexpr int S1_LDS = (32*600 + 64*600) * 2 + 32*68*4 + 256*8*4 + 3*256*4;   // 135168

#define DEVI __device__ __forceinline__

typedef __attribute__((ext_vector_type(8))) short short8v;   // 8 bf16 (4 VGPRs)
typedef __attribute__((ext_vector_type(4))) float f32x4;     // MFMA acc

DEVI float sigm(float x) {
    x = fminf(30.f, fmaxf(-30.f, x));
    return 1.f / (1.f + __expf(-x));
}
DEVI float tanh_f(float x) {
    x = fminf(15.f, fmaxf(-15.f, x));
    float t = __expf(2.f * x);
    return (t - 1.f) / (t + 1.f);
}
DEVI uint16_t f2bf(float f) {  // RNE fp32->bf16
    uint32_t u = __float_as_uint(f);
    return (uint16_t)((u + 0x7fffu + ((u >> 16) & 1u)) >> 16);
}

DEVI int ld_agent(const int* p) {
    return __hip_atomic_load(p, __ATOMIC_RELAXED, __HIP_MEMORY_SCOPE_AGENT);
}
DEVI unsigned int ldu_agent(const unsigned int* p) {
    return __hip_atomic_load(p, __ATOMIC_RELAXED, __HIP_MEMORY_SCOPE_AGENT);
}
DEVI float ldf_agent(const float* p) {
    return __hip_atomic_load(p, __ATOMIC_RELAXED, __HIP_MEMORY_SCOPE_AGENT);
}
DEVI void stu_agent(unsigned int* p, unsigned int v) {
    __hip_atomic_store(p, v, __ATOMIC_RELAXED, __HIP_MEMORY_SCOPE_AGENT);
}
DEVI void stf_agent(float* p, float v) {
    __hip_atomic_store(p, v, __ATOMIC_RELAXED, __HIP_MEMORY_SCOPE_AGENT);
}

// ---- fence-free device barrier: relaxed atomics only; data moves via sc-flagged ops ----
// Correctness: writers' sc-stores drained by the __syncthreads (per-wave vmcnt(0)) BEFORE
// the arrive-RMW; arrive -> root -> go all execute at the device coherence point; readers'
// sc-loads also read the coherence point. No buffer_wbl2 / buffer_inv anywhere.
// area ints: arrive[b] @ b*32 ; root @ 600 ; go[b] @ 1024 + b*32.
DEVI void barrier3(int* area, int wgid, int nb, int pb, int phase) {
    __syncthreads();   // all waves' outstanding global (sc) stores retired
    if (threadIdx.x == 0) {
        const int b = wgid % nb;
        int old = __hip_atomic_fetch_add(&area[b * 32], 1,
                                         __ATOMIC_RELAXED, __HIP_MEMORY_SCOPE_AGENT);
        if ((old % pb) == pb - 1) {
            int old2 = __hip_atomic_fetch_add(&area[600], 1,
                                              __ATOMIC_RELAXED, __HIP_MEMORY_SCOPE_AGENT);
            if ((old2 % nb) == nb - 1) {           // last arriver overall -> releaser
                for (int i = 0; i < nb; ++i)
                    stu_agent((unsigned int*)&area[1024 + i * 32], (unsigned int)(phase + 1));
            }
        }
        while (ld_agent(&area[1024 + b * 32]) < phase + 1)
            __builtin_amdgcn_s_sleep(1);
    }
    __syncthreads();
}

// ---------------- generic fp32 GEMM: out[t][r] = act(X[t]·W[r] + bA[r] (+ bB[r])) ----------------
template <int TBLK>
__global__ void __launch_bounds__(256) gemm_rows(
    const float* __restrict__ X, int T, int K,
    const float* __restrict__ W, int R,
    const float* __restrict__ bA, const float* __restrict__ bB,
    float* __restrict__ out, int act)
{
    __shared__ float xt[TBLK][448];
    const int r  = blockIdx.x * 256 + threadIdx.x;
    const int t0 = blockIdx.y * TBLK;
    float acc[TBLK];
#pragma unroll
    for (int i = 0; i < TBLK; ++i) acc[i] = 0.f;

    for (int kc0 = 0; kc0 < K; kc0 += 448) {
        const int kc  = (K - kc0 < 448) ? (K - kc0) : 448;
        const int kc4 = kc >> 2;
        __syncthreads();
        for (int idx = threadIdx.x; idx < TBLK * kc4; idx += 256) {
            int tt = idx / kc4, kk = idx - tt * kc4;
            float4 v = make_float4(0.f, 0.f, 0.f, 0.f);
            if (t0 + tt < T)
                v = *(const float4*)(X + (size_t)(t0 + tt) * K + kc0 + kk * 4);
            *(float4*)(&xt[tt][kk * 4]) = v;
        }
        __syncthreads();
        if (r < R) {
            const float4* wr = (const float4*)(W + (size_t)r * K + kc0);
            for (int k4 = 0; k4 < kc4; ++k4) {
                float4 w4 = wr[k4];
#pragma unroll
                for (int tt = 0; tt < TBLK; ++tt) {
                    float4 x4 = *(const float4*)(&xt[tt][k4 * 4]);
                    acc[tt] = fmaf(w4.x, x4.x, acc[tt]);
                    acc[tt] = fmaf(w4.y, x4.y, acc[tt]);
                    acc[tt] = fmaf(w4.z, x4.z, acc[tt]);
                    acc[tt] = fmaf(w4.w, x4.w, acc[tt]);
                }
            }
        }
    }
    if (r < R) {
        float bb = bA[r] + (bB ? bB[r] : 0.f);
#pragma unroll
        for (int tt = 0; tt < TBLK; ++tt) {
            if (t0 + tt < T) {
                float v = acc[tt] + bb;
                if (act) v = tanh_f(v);
                out[(size_t)(t0 + tt) * R + r] = v;
            }
        }
    }
}

// ---------------- segment starts + length-sort (1 block, 256 threads) ----------------
__global__ void __launch_bounds__(256) k_start(
    const float* __restrict__ action, const int* __restrict__ apos, int* __restrict__ meta)
{
    __shared__ int Lsh[256];
    const int p = threadIdx.x;
    const int pos = apos[p];
    int u = pos;
    while (u > 0 && action[u - 1] == 0.0f) --u;
    const int L = pos - u + 1;
    meta[p] = u;
    meta[256 + p] = L;
    Lsh[p] = L;
    __syncthreads();
    int rank = 0;
    for (int q = 0; q < 256; ++q) {
        int Lq = Lsh[q];
        if (Lq > L || (Lq == L && q < p)) ++rank;
    }
    meta[512 + rank] = p;
    meta[768 + rank] = L;
    if (rank == 0) meta[1024] = L;
}

// ---------------- stage-1 LSTM via MFMA: 75 wgs x 8 units, chains lockstep ----------------
__global__ void __launch_bounds__(512) k_s1(
    const float* __restrict__ X1, const float* __restrict__ Whh1,
    const int* __restrict__ meta,
    unsigned short* __restrict__ Hbf, float* __restrict__ EMB,
    int* __restrict__ sync)
{
    extern __shared__ char smem[];
    unsigned short* wl = (unsigned short*)smem;            // [32][600] bf16
    unsigned short* hl = wl + 32 * 600;                    // [64][600] bf16
    float* glds = (float*)(hl + 64 * 600);                 // [32][68] gates
    float* clds = glds + 32 * 68;                          // [256][8] c-state
    int* ordC  = (int*)(clds + 256 * 8);
    int* ordST = ordC + 256;
    int* ordL  = ordST + 256;

    const int wg  = blockIdx.x;        // 0..74, owns units u0..u0+7
    const int u0  = wg * 8;
    const int tid = threadIdx.x;
    const int lane = tid & 63;
    const int w  = tid >> 6;
    const int ct = w & 3, rt = w >> 2;

    for (int idx = tid; idx < 32 * 150; idx += 512) {
        int rr = idx / 150, j = idx - rr * 150;
        int gamma = rr >> 3, u = rr & 7;
        float4 v = *(const float4*)(Whh1 + (size_t)(gamma * 600 + u0 + u) * 600 + j * 4);
        ushort4 pk = make_ushort4(f2bf(v.x), f2bf(v.y), f2bf(v.z), f2bf(v.w));
        *(ushort4*)(wl + rr * 600 + j * 4) = pk;
    }
    if (tid < 256) {
        int p = meta[512 + tid];
        ordC[tid]  = p;
        ordST[tid] = meta[p];
        ordL[tid]  = meta[256 + p];
    }
    for (int idx = tid; idx < 2048; idx += 512) clds[idx] = 0.f;
    __syncthreads();

    const int lmax = ordL[0];
    int A = 256;

    for (int k = 0; k < lmax; ++k) {
        while (A > 0 && ordL[A - 1] <= k) --A;
        const int rb = k & 1;
        const unsigned short* Hr = Hbf + (size_t)rb * PSEQ * NH1;
        unsigned short*       Hw = Hbf + (size_t)(rb ^ 1) * PSEQ * NH1;
        const int ng = (A + 63) >> 6;

        for (int g = 0; g < ng; ++g) {
            const int sc  = (A - g * 64 < 64) ? (A - g * 64) : 64;
            const int nst = (sc + 15) & ~15;
            __syncthreads();
            // stage h (bf16) via coherent uint loads (2 bf16 per load)
            for (int idx = tid; idx < nst * 300; idx += 512) {
                int ci = idx / 300, j2 = idx - ci * 300;
                int ch = ordC[g * 64 + ci];
                unsigned int v = ldu_agent((const unsigned int*)(Hr + (size_t)ch * 600) + j2);
                *((unsigned int*)(hl + (size_t)ci * 600) + j2) = v;
            }
            __syncthreads();

            // epilogue-role prefetch: X1 gate values + meta (independent of h)
            const int s_loc = tid >> 3, eu = tid & 7;
            const bool ep = (s_loc < sc);
            int ch = 0, st = 0, L = 0;
            float xv0 = 0, xv1 = 0, xv2 = 0, xv3 = 0;
            if (ep) {
                ch = ordC[g * 64 + s_loc];
                st = ordST[g * 64 + s_loc];
                L  = ordL[g * 64 + s_loc];
                const float* xr = X1 + (size_t)(st + k) * 2400 + u0 + eu;
                xv0 = xr[0]; xv1 = xr[600]; xv2 = xr[1200]; xv3 = xr[1800];
            }

            // MFMA: D[chain][row] += h · W^T
            if (ct * 16 < sc) {
                f32x4 acc = {0.f, 0.f, 0.f, 0.f};
                const int kg = lane >> 4;
                const short* ha = (const short*)hl + (ct * 16 + (lane & 15)) * 600;
                const short* wb = (const short*)wl + (rt * 16 + (lane & 15)) * 600;
#pragma unroll
                for (int kt = 0; kt < 19; ++kt) {
                    int k0 = kt * 32 + kg * 8;
                    short8v af = {0, 0, 0, 0, 0, 0, 0, 0};
                    short8v bf = {0, 0, 0, 0, 0, 0, 0, 0};
                    if (k0 < 600) {
                        af = *(const short8v*)(ha + k0);
                        bf = *(const short8v*)(wb + k0);
                    }
                    acc = __builtin_amdgcn_mfma_f32_16x16x32_bf16(af, bf, acc, 0, 0, 0);
                }
                const int brow = rt * 16 + (lane & 15);
                const int ch0  = ct * 16 + ((lane >> 4) << 2);
                *(f32x4*)(glds + brow * 68 + ch0) = acc;
            }
            __syncthreads();

            // gate epilogue: compute unconditionally (safe garbage), guard stores with ep
            {
                float gi = glds[(0 * 8 + eu) * 68 + s_loc] + xv0;
                float gf = glds[(1 * 8 + eu) * 68 + s_loc] + xv1;
                float gg = glds[(2 * 8 + eu) * 68 + s_loc] + xv2;
                float go = glds[(3 * 8 + eu) * 68 + s_loc] + xv3;
                float co = clds[ch * 8 + eu];
                float cn = sigm(gf) * co + sigm(gi) * tanh_f(gg);
                float hn = sigm(go) * tanh_f(cn);
                if (ep) clds[ch * 8 + eu] = cn;
                unsigned int pk = (unsigned int)f2bf(hn);
                unsigned int hi = __shfl_down(pk, 1, 64);
                if (ep && (eu & 1) == 0)
                    stu_agent((unsigned int*)(Hw + (size_t)ch * 600 + u0 + eu), pk | (hi << 16));
                if (ep && k == L - 1)
                    EMB[(size_t)ch * 600 + u0 + eu] = hn;
            }
        }
        if (k < lmax - 1) barrier3(sync, wg, 15, 5, k);   // 75 = 15 buckets x 5
    }
}

// ---------------- stage-2 LSTM: 256 wgs x 8 units; 512 thr; wave w owns unit w ----------------
__global__ void __launch_bounds__(512) k_s2(
    const float* __restrict__ X2, const float* __restrict__ Whh2,
    float* __restrict__ h2, float* __restrict__ PH, int* __restrict__ sync)
{
    __shared__ float hl[NH2];
    const int wg   = blockIdx.x;
    const int tid  = threadIdx.x;
    const int lane = tid & 63;
    const int w    = tid >> 6;         // wave = unit 0..7
    const int uu   = wg * 8 + w;
    int* syncg = sync + 2048;

    // preload 4 gate rows fp32 into VGPRs: wv[g][j*4+c] = Whh2[g*2048+uu][j*256+lane*4+c]
    float wv[4][32];
#pragma unroll
    for (int g = 0; g < 4; ++g) {
        const float* rp = Whh2 + ((size_t)(g * NH2 + uu)) * NH2 + lane * 4;
#pragma unroll
        for (int j = 0; j < 8; ++j) {
            float4 a = *(const float4*)(rp + j * 256);
            wv[g][j * 4 + 0] = a.x; wv[g][j * 4 + 1] = a.y;
            wv[g][j * 4 + 2] = a.z; wv[g][j * 4 + 3] = a.w;
        }
    }
    *(float4*)(hl + tid * 4) = make_float4(0.f, 0.f, 0.f, 0.f);
    float creg = 0.f;
    __syncthreads();

    for (int t = 0; t < PSEQ; ++t) {
        // prefetch x gate values (lane0 of each wave), independent of h
        float x0 = 0, x1 = 0, x2 = 0, x3 = 0;
        if (lane == 0) {
            const float* xr = X2 + (size_t)t * (4 * NH2) + uu;
            x0 = xr[0]; x1 = xr[NH2]; x2 = xr[2 * NH2]; x3 = xr[3 * NH2];
        }
        float a0 = 0, a1 = 0, a2 = 0, a3 = 0;
#pragma unroll
        for (int j = 0; j < 8; ++j) {
            float4 hv = *(const float4*)(hl + j * 256 + lane * 4);
            a0 = fmaf(wv[0][j*4+0], hv.x, a0); a0 = fmaf(wv[0][j*4+1], hv.y, a0);
            a0 = fmaf(wv[0][j*4+2], hv.z, a0); a0 = fmaf(wv[0][j*4+3], hv.w, a0);
            a1 = fmaf(wv[1][j*4+0], hv.x, a1); a1 = fmaf(wv[1][j*4+1], hv.y, a1);
            a1 = fmaf(wv[1][j*4+2], hv.z, a1); a1 = fmaf(wv[1][j*4+3], hv.w, a1);
            a2 = fmaf(wv[2][j*4+0], hv.x, a2); a2 = fmaf(wv[2][j*4+1], hv.y, a2);
            a2 = fmaf(wv[2][j*4+2], hv.z, a2); a2 = fmaf(wv[2][j*4+3], hv.w, a2);
            a3 = fmaf(wv[3][j*4+0], hv.x, a3); a3 = fmaf(wv[3][j*4+1], hv.y, a3);
            a3 = fmaf(wv[3][j*4+2], hv.z, a3); a3 = fmaf(wv[3][j*4+3], hv.w, a3);
        }
#pragma unroll
        for (int m = 32; m > 0; m >>= 1) {
            a0 += __shfl_xor(a0, m, 64); a1 += __shfl_xor(a1, m, 64);
            a2 += __shfl_xor(a2, m, 64); a3 += __shfl_xor(a3, m, 64);
        }
        if (lane == 0) {
            float gi = a0 + x0, gf = a1 + x1, gg = a2 + x2, go = a3 + x3;
            float cn = sigm(gf) * creg + sigm(gi) * tanh_f(gg);
            float hn = sigm(go) * tanh_f(cn);
            creg = cn;
            stf_agent(h2 + ((t + 1) & 1) * NH2 + uu, hn);   // coherent write-through
            PH[(size_t)t * NH2 + uu] = hn;
        }
        if (t < PSEQ - 1) {
            barrier3(syncg, wg, 16, 16, t);   // 256 = 16 x 16
            // stage next h: 4 coherent dword loads per thread -> LDS
            const float* hb = h2 + ((t + 1) & 1) * NH2 + tid * 4;
            float4 hv;
            hv.x = ldf_agent(hb + 0);
            hv.y = ldf_agent(hb + 1);
            hv.z = ldf_agent(hb + 2);
            hv.w = ldf_agent(hb + 3);
            *(float4*)(hl + tid * 4) = hv;
            __syncthreads();
        }
    }
}

// ---------------- column sum of S -> SSUM ----------------
__global__ void __launch_bounds__(256) k_colsum(const float* __restrict__ S, float* __restrict__ out)
{
    const int j = blockIdx.x * 256 + threadIdx.x;
    float a = 0.f;
    for (int t = 0; t < PSEQ; ++t) a += S[(size_t)t * NH2 + j];
    out[j] = a;
}

// ---------------- matvec: vout[r] = W[r]·vin + bscale*b[r] ----------------
__global__ void __launch_bounds__(256) k_mv(
    const float* __restrict__ W, const float* __restrict__ b, float bscale,
    const float* __restrict__ vin, float* __restrict__ vout)
{
    __shared__ float v[NH2];
    for (int i = threadIdx.x; i < NH2; i += 256) v[i] = vin[i];
    __syncthreads();
    const int r = blockIdx.x * 256 + threadIdx.x;
    const float4* wr = (const float4*)(W + (size_t)r * NH2);
    float a0 = 0, a1 = 0, a2 = 0, a3 = 0;
    for (int k4 = 0; k4 < NH2 / 4; ++k4) {
        float4 w4 = wr[k4];
        float4 x4 = *(const float4*)(&v[k4 * 4]);
        a0 = fmaf(w4.x, x4.x, a0); a1 = fmaf(w4.y, x4.y, a1);
        a2 = fmaf(w4.z, x4.z, a2); a3 = fmaf(w4.w, x4.w, a3);
    }
    vout[r] = (a0 + a1) + (a2 + a3) + bscale * b[r];
}

extern "C" void kernel_launch(void* const* d_in, const int* in_sizes, int n_in,
                              void* d_out, int out_size, void* d_ws, size_t ws_size,
                              hipStream_t stream)
{
    const float* sent   = (const float*)d_in[0];
    const float* action = (const float*)d_in[1];
    const int*   apos   = (const int*)  d_in[2];
    const float* Wih1   = (const float*)d_in[3];
    const float* Whh1   = (const float*)d_in[4];
    const float* bih1   = (const float*)d_in[5];
    const float* bhh1   = (const float*)d_in[6];
    const float* W1     = (const float*)d_in[7];
    const float* b1     = (const float*)d_in[8];
    const float* Wih2   = (const float*)d_in[9];
    const float* Whh2   = (const float*)d_in[10];
    const float* bih2   = (const float*)d_in[11];
    const float* bhh2   = (const float*)d_in[12];
    const float* W2     = (const float*)d_in[13];
    const float* b2     = (const float*)d_in[14];
    const float* ipw    = (const float*)d_in[15];
    const float* ipb    = (const float*)d_in[16];
    const float* opw    = (const float*)d_in[17];
    const float* opb    = (const float*)d_in[18];

    char* ws = (char*)d_ws;
    float*          X1   = (float*)(ws + OFF_X1);
    unsigned short* HBF  = (unsigned short*)(ws + OFF_HBF);
    float*          EMB  = (float*)(ws + OFF_EMB);
    float*          EMB2 = (float*)(ws + OFF_EMB2);
    float*          X2   = (float*)(ws + OFF_X2);
    float*          PH   = (float*)(ws + OFF_PH);
    float*          S    = (float*)(ws + OFF_S);
    float*          H2   = (float*)(ws + OFF_H2);
    float*          SSUM = (float*)(ws + OFF_SSUM);
    float*          TMP  = (float*)(ws + OFF_TMP);
    int*            META = (int*)  (ws + OFF_META);
    int*            SYNC = (int*)  (ws + OFF_SYNC);

    // re-zero stateful buffers every call (graph replays)
    hipMemsetAsync(ws + OFF_HBF, 0, SZ_HBF, stream);
    hipMemsetAsync(ws + OFF_SYNC, 0, SZ_SYNC, stream);

    hipFuncSetAttribute((const void*)k_s1, hipFuncAttributeMaxDynamicSharedMemorySize, S1_LDS);

    // X1 = sent @ Wih1.T + bih1 + bhh1   (2048 x 2400, K=300)
    gemm_rows<32><<<dim3(10, 64), 256, 0, stream>>>(sent, TSEQ, DIN, Wih1, 4 * NH1, bih1, bhh1, X1, 0);
    // segment starts / lengths / sort
    k_start<<<1, 256, 0, stream>>>(action, apos, META);
    // stage-1 chains (MFMA) -> EMB
    k_s1<<<75, 512, S1_LDS, stream>>>(X1, Whh1, META, HBF, EMB, SYNC);
    // EMB2 = tanh(EMB @ W1.T + b1)       (256 x 600, K=600)
    gemm_rows<8><<<dim3(3, 32), 256, 0, stream>>>(EMB, PSEQ, NH1, W1, NH1, b1, nullptr, EMB2, 1);
    // X2 = EMB2 @ Wih2.T + bih2 + bhh2   (256 x 8192, K=600)
    gemm_rows<32><<<dim3(32, 8), 256, 0, stream>>>(EMB2, PSEQ, NH1, Wih2, 4 * NH2, bih2, bhh2, X2, 0);
    // stage-2 LSTM -> PH (256 x 2048)
    k_s2<<<256, 512, 0, stream>>>(X2, Whh2, H2, PH, SYNC);
    // S = tanh(PH @ W2.T + b2)           (256 x 2048, K=2048)
    gemm_rows<8><<<dim3(8, 32), 256, 0, stream>>>(PH, PSEQ, NH2, W2, NH2, b2, nullptr, S, 1);
    // SSUM = column sums of S
    k_colsum<<<8, 256, 0, stream>>>(S, SSUM);
    // attention collapse: out = (SSUM @ Wv.T + 256*bv) @ Wo.T + 256*bo
    k_mv<<<8, 256, 0, stream>>>(ipw + (size_t)4096 * NH2, ipb + 4096, 256.f, SSUM, TMP);
    k_mv<<<8, 256, 0, stream>>>(opw, opb, 256.f, TMP, (float*)d_out);
}

// Round 4
// 2246.051 us; speedup vs baseline: 2.3287x; 1.0011x over previous
//
#include <hip/hip_runtime.h>
#include <cstdint>
#include <cstddef>

// ---------------- problem constants ----------------
static constexpr int TSEQ = 2048;   // T
static constexpr int PSEQ = 256;    // P
static constexpr int DIN  = 300;
static constexpr int NH1  = 600;
static constexpr int NH2  = 2048;

// ---------------- ws layout (bytes) ----------------
static constexpr size_t OFF_X1   = 0;                                   // [2048][2400] f32
static constexpr size_t SZ_X1    = (size_t)TSEQ * 4 * NH1 * 4;
static constexpr size_t OFF_HBF  = OFF_X1 + SZ_X1;                      // [2][256][600] bf16 dbl-buf
static constexpr size_t SZ_HBF   = 2ull * PSEQ * NH1 * 2;
static constexpr size_t OFF_EMB  = OFF_HBF + SZ_HBF;                    // [256][600] f32
static constexpr size_t SZ_EMB   = (size_t)PSEQ * NH1 * 4;
static constexpr size_t OFF_EMB2 = OFF_EMB + SZ_EMB;                    // [256][600] f32
static constexpr size_t SZ_EMB2  = (size_t)PSEQ * NH1 * 4;
static constexpr size_t OFF_X2   = OFF_EMB2 + SZ_EMB2;                  // [256][8192] f32
static constexpr size_t SZ_X2    = (size_t)PSEQ * 4 * NH2 * 4;
static constexpr size_t OFF_PH   = OFF_X2 + SZ_X2;                      // [256][2048] f32
static constexpr size_t SZ_PH    = (size_t)PSEQ * NH2 * 4;
static constexpr size_t OFF_S    = OFF_PH + SZ_PH;                      // [256][2048] f32
static constexpr size_t SZ_S     = (size_t)PSEQ * NH2 * 4;
static constexpr size_t OFF_H2   = OFF_S + SZ_S;                        // [2][2048] f32
static constexpr size_t SZ_H2    = 2ull * NH2 * 4;
static constexpr size_t OFF_SSUM = OFF_H2 + SZ_H2;                      // 2048 f32
static constexpr size_t OFF_TMP  = OFF_SSUM + 8192;                     // 2048 f32
static constexpr size_t OFF_META = OFF_TMP + 8192;                      // ints: st[256] L[256] ord[256] Ls[256] lmax
static constexpr size_t OFF_SYNC = OFF_META + 8192;                     // barrier counters (2 regions x 2048 ints)
static constexpr size_t SZ_SYNC  = 16384;

// k_s1 dynamic LDS: W 32x600 bf16 + h 64x600 bf16 + g 32x68 f32 + c 256x8 f32 + meta 3x256 int
static constexpr int S1_LDS = (32*600 + 64*600) * 2 + 32*68*4 + 256*8*4 + 3*256*4;   // 135168

#define DEVI __device__ __forceinline__

typedef __attribute__((ext_vector_type(8))) short short8v;   // 8 bf16 (4 VGPRs)
typedef __attribute__((ext_vector_type(4))) float f32x4;     // MFMA acc

DEVI float sigm(float x) {
    x = fminf(30.f, fmaxf(-30.f, x));
    return 1.f / (1.f + __expf(-x));
}
DEVI float tanh_f(float x) {
    x = fminf(15.f, fmaxf(-15.f, x));
    float t = __expf(2.f * x);
    return (t - 1.f) / (t + 1.f);
}
DEVI uint16_t f2bf(float f) {  // RNE fp32->bf16
    uint32_t u = __float_as_uint(f);
    return (uint16_t)((u + 0x7fffu + ((u >> 16) & 1u)) >> 16);
}

DEVI int ld_agent(const int* p) {
    return __hip_atomic_load(p, __ATOMIC_RELAXED, __HIP_MEMORY_SCOPE_AGENT);
}
DEVI unsigned int ldu_agent(const unsigned int* p) {
    return __hip_atomic_load(p, __ATOMIC_RELAXED, __HIP_MEMORY_SCOPE_AGENT);
}
DEVI float ldf_agent(const float* p) {
    return __hip_atomic_load(p, __ATOMIC_RELAXED, __HIP_MEMORY_SCOPE_AGENT);
}
DEVI void stu_agent(unsigned int* p, unsigned int v) {
    __hip_atomic_store(p, v, __ATOMIC_RELAXED, __HIP_MEMORY_SCOPE_AGENT);
}
DEVI void stf_agent(float* p, float v) {
    __hip_atomic_store(p, v, __ATOMIC_RELAXED, __HIP_MEMORY_SCOPE_AGENT);
}

// ---- fence-free device barrier: relaxed atomics only; data moves via sc-flagged ops ----
// Correctness: writers' sc-stores drained by the __syncthreads (per-wave vmcnt(0)) BEFORE
// the arrive-RMW; arrive -> root -> go all execute at the device coherence point; readers'
// sc-loads also read the coherence point. No buffer_wbl2 / buffer_inv anywhere.
// area ints: arrive[b] @ b*32 ; root @ 600 ; go[b] @ 1024 + b*32.
DEVI void barrier3(int* area, int wgid, int nb, int pb, int phase) {
    __syncthreads();   // all waves' outstanding global (sc) stores retired
    if (threadIdx.x == 0) {
        const int b = wgid % nb;
        int old = __hip_atomic_fetch_add(&area[b * 32], 1,
                                         __ATOMIC_RELAXED, __HIP_MEMORY_SCOPE_AGENT);
        if ((old % pb) == pb - 1) {
            int old2 = __hip_atomic_fetch_add(&area[600], 1,
                                              __ATOMIC_RELAXED, __HIP_MEMORY_SCOPE_AGENT);
            if ((old2 % nb) == nb - 1) {           // last arriver overall -> releaser
                for (int i = 0; i < nb; ++i)
                    stu_agent((unsigned int*)&area[1024 + i * 32], (unsigned int)(phase + 1));
            }
        }
        while (ld_agent(&area[1024 + b * 32]) < phase + 1)
            __builtin_amdgcn_s_sleep(1);
    }
    __syncthreads();
}

// ---------------- generic fp32 GEMM: out[t][r] = act(X[t]·W[r] + bA[r] (+ bB[r])) ----------------
template <int TBLK>
__global__ void __launch_bounds__(256) gemm_rows(
    const float* __restrict__ X, int T, int K,
    const float* __restrict__ W, int R,
    const float* __restrict__ bA, const float* __restrict__ bB,
    float* __restrict__ out, int act)
{
    __shared__ float xt[TBLK][448];
    const int r  = blockIdx.x * 256 + threadIdx.x;
    const int t0 = blockIdx.y * TBLK;
    float acc[TBLK];
#pragma unroll
    for (int i = 0; i < TBLK; ++i) acc[i] = 0.f;

    for (int kc0 = 0; kc0 < K; kc0 += 448) {
        const int kc  = (K - kc0 < 448) ? (K - kc0) : 448;
        const int kc4 = kc >> 2;
        __syncthreads();
        for (int idx = threadIdx.x; idx < TBLK * kc4; idx += 256) {
            int tt = idx / kc4, kk = idx - tt * kc4;
            float4 v = make_float4(0.f, 0.f, 0.f, 0.f);
            if (t0 + tt < T)
                v = *(const float4*)(X + (size_t)(t0 + tt) * K + kc0 + kk * 4);
            *(float4*)(&xt[tt][kk * 4]) = v;
        }
        __syncthreads();
        if (r < R) {
            const float4* wr = (const float4*)(W + (size_t)r * K + kc0);
            for (int k4 = 0; k4 < kc4; ++k4) {
                float4 w4 = wr[k4];
#pragma unroll
                for (int tt = 0; tt < TBLK; ++tt) {
                    float4 x4 = *(const float4*)(&xt[tt][k4 * 4]);
                    acc[tt] = fmaf(w4.x, x4.x, acc[tt]);
                    acc[tt] = fmaf(w4.y, x4.y, acc[tt]);
                    acc[tt] = fmaf(w4.z, x4.z, acc[tt]);
                    acc[tt] = fmaf(w4.w, x4.w, acc[tt]);
                }
            }
        }
    }
    if (r < R) {
        float bb = bA[r] + (bB ? bB[r] : 0.f);
#pragma unroll
        for (int tt = 0; tt < TBLK; ++tt) {
            if (t0 + tt < T) {
                float v = acc[tt] + bb;
                if (act) v = tanh_f(v);
                out[(size_t)(t0 + tt) * R + r] = v;
            }
        }
    }
}

// ---------------- segment starts + length-sort (1 block, 256 threads) ----------------
__global__ void __launch_bounds__(256) k_start(
    const float* __restrict__ action, const int* __restrict__ apos, int* __restrict__ meta)
{
    __shared__ int Lsh[256];
    const int p = threadIdx.x;
    const int pos = apos[p];
    int u = pos;
    while (u > 0 && action[u - 1] == 0.0f) --u;
    const int L = pos - u + 1;
    meta[p] = u;
    meta[256 + p] = L;
    Lsh[p] = L;
    __syncthreads();
    int rank = 0;
    for (int q = 0; q < 256; ++q) {
        int Lq = Lsh[q];
        if (Lq > L || (Lq == L && q < p)) ++rank;
    }
    meta[512 + rank] = p;
    meta[768 + rank] = L;
    if (rank == 0) meta[1024] = L;
}

// ---------------- stage-1 LSTM via MFMA: 75 wgs x 8 units, chains lockstep ----------------
__global__ void __launch_bounds__(512) k_s1(
    const float* __restrict__ X1, const float* __restrict__ Whh1,
    const int* __restrict__ meta,
    unsigned short* __restrict__ Hbf, float* __restrict__ EMB,
    int* __restrict__ sync)
{
    extern __shared__ char smem[];
    unsigned short* wl = (unsigned short*)smem;            // [32][600] bf16
    unsigned short* hl = wl + 32 * 600;                    // [64][600] bf16
    float* glds = (float*)(hl + 64 * 600);                 // [32][68] gates
    float* clds = glds + 32 * 68;                          // [256][8] c-state
    int* ordC  = (int*)(clds + 256 * 8);
    int* ordST = ordC + 256;
    int* ordL  = ordST + 256;

    const int wg  = blockIdx.x;        // 0..74, owns units u0..u0+7
    const int u0  = wg * 8;
    const int tid = threadIdx.x;
    const int lane = tid & 63;
    const int w  = tid >> 6;
    const int ct = w & 3, rt = w >> 2;

    for (int idx = tid; idx < 32 * 150; idx += 512) {
        int rr = idx / 150, j = idx - rr * 150;
        int gamma = rr >> 3, u = rr & 7;
        float4 v = *(const float4*)(Whh1 + (size_t)(gamma * 600 + u0 + u) * 600 + j * 4);
        ushort4 pk = make_ushort4(f2bf(v.x), f2bf(v.y), f2bf(v.z), f2bf(v.w));
        *(ushort4*)(wl + rr * 600 + j * 4) = pk;
    }
    if (tid < 256) {
        int p = meta[512 + tid];
        ordC[tid]  = p;
        ordST[tid] = meta[p];
        ordL[tid]  = meta[256 + p];
    }
    for (int idx = tid; idx < 2048; idx += 512) clds[idx] = 0.f;
    __syncthreads();

    const int lmax = ordL[0];
    int A = 256;

    for (int k = 0; k < lmax; ++k) {
        while (A > 0 && ordL[A - 1] <= k) --A;
        const int rb = k & 1;
        const unsigned short* Hr = Hbf + (size_t)rb * PSEQ * NH1;
        unsigned short*       Hw = Hbf + (size_t)(rb ^ 1) * PSEQ * NH1;
        const int ng = (A + 63) >> 6;

        for (int g = 0; g < ng; ++g) {
            const int sc  = (A - g * 64 < 64) ? (A - g * 64) : 64;
            const int nst = (sc + 15) & ~15;
            __syncthreads();
            // stage h (bf16) via coherent uint loads (2 bf16 per load)
            for (int idx = tid; idx < nst * 300; idx += 512) {
                int ci = idx / 300, j2 = idx - ci * 300;
                int ch = ordC[g * 64 + ci];
                unsigned int v = ldu_agent((const unsigned int*)(Hr + (size_t)ch * 600) + j2);
                *((unsigned int*)(hl + (size_t)ci * 600) + j2) = v;
            }
            __syncthreads();

            // epilogue-role prefetch: X1 gate values + meta (independent of h)
            const int s_loc = tid >> 3, eu = tid & 7;
            const bool ep = (s_loc < sc);
            int ch = 0, st = 0, L = 0;
            float xv0 = 0, xv1 = 0, xv2 = 0, xv3 = 0;
            if (ep) {
                ch = ordC[g * 64 + s_loc];
                st = ordST[g * 64 + s_loc];
                L  = ordL[g * 64 + s_loc];
                const float* xr = X1 + (size_t)(st + k) * 2400 + u0 + eu;
                xv0 = xr[0]; xv1 = xr[600]; xv2 = xr[1200]; xv3 = xr[1800];
            }

            // MFMA: D[chain][row] += h · W^T
            if (ct * 16 < sc) {
                f32x4 acc = {0.f, 0.f, 0.f, 0.f};
                const int kg = lane >> 4;
                const short* ha = (const short*)hl + (ct * 16 + (lane & 15)) * 600;
                const short* wb = (const short*)wl + (rt * 16 + (lane & 15)) * 600;
#pragma unroll
                for (int kt = 0; kt < 19; ++kt) {
                    int k0 = kt * 32 + kg * 8;
                    short8v af = {0, 0, 0, 0, 0, 0, 0, 0};
                    short8v bf = {0, 0, 0, 0, 0, 0, 0, 0};
                    if (k0 < 600) {
                        af = *(const short8v*)(ha + k0);
                        bf = *(const short8v*)(wb + k0);
                    }
                    acc = __builtin_amdgcn_mfma_f32_16x16x32_bf16(af, bf, acc, 0, 0, 0);
                }
                const int brow = rt * 16 + (lane & 15);
                const int ch0  = ct * 16 + ((lane >> 4) << 2);
                *(f32x4*)(glds + brow * 68 + ch0) = acc;
            }
            __syncthreads();

            // gate epilogue: compute unconditionally (safe garbage), guard stores with ep
            {
                float gi = glds[(0 * 8 + eu) * 68 + s_loc] + xv0;
                float gf = glds[(1 * 8 + eu) * 68 + s_loc] + xv1;
                float gg = glds[(2 * 8 + eu) * 68 + s_loc] + xv2;
                float go = glds[(3 * 8 + eu) * 68 + s_loc] + xv3;
                float co = clds[ch * 8 + eu];
                float cn = sigm(gf) * co + sigm(gi) * tanh_f(gg);
                float hn = sigm(go) * tanh_f(cn);
                if (ep) clds[ch * 8 + eu] = cn;
                unsigned int pk = (unsigned int)f2bf(hn);
                unsigned int hi = __shfl_down(pk, 1, 64);
                if (ep && (eu & 1) == 0)
                    stu_agent((unsigned int*)(Hw + (size_t)ch * 600 + u0 + eu), pk | (hi << 16));
                if (ep && k == L - 1)
                    EMB[(size_t)ch * 600 + u0 + eu] = hn;
            }
        }
        if (k < lmax - 1) barrier3(sync, wg, 15, 5, k);   // 75 = 15 buckets x 5
    }
}

// ---------------- stage-2 LSTM: 256 wgs x 8 units; 512 thr; wave w owns unit w ----------------
__global__ void __launch_bounds__(512) k_s2(
    const float* __restrict__ X2, const float* __restrict__ Whh2,
    float* __restrict__ h2, float* __restrict__ PH, int* __restrict__ sync)
{
    __shared__ float hl[NH2];
    const int wg   = blockIdx.x;
    const int tid  = threadIdx.x;
    const int lane = tid & 63;
    const int w    = tid >> 6;         // wave = unit 0..7
    const int uu   = wg * 8 + w;
    int* syncg = sync + 2048;

    // preload 4 gate rows fp32 into VGPRs: wv[g][j*4+c] = Whh2[g*2048+uu][j*256+lane*4+c]
    float wv[4][32];
#pragma unroll
    for (int g = 0; g < 4; ++g) {
        const float* rp = Whh2 + ((size_t)(g * NH2 + uu)) * NH2 + lane * 4;
#pragma unroll
        for (int j = 0; j < 8; ++j) {
            float4 a = *(const float4*)(rp + j * 256);
            wv[g][j * 4 + 0] = a.x; wv[g][j * 4 + 1] = a.y;
            wv[g][j * 4 + 2] = a.z; wv[g][j * 4 + 3] = a.w;
        }
    }
    *(float4*)(hl + tid * 4) = make_float4(0.f, 0.f, 0.f, 0.f);
    float creg = 0.f;
    __syncthreads();

    for (int t = 0; t < PSEQ; ++t) {
        // prefetch x gate values (lane0 of each wave), independent of h
        float x0 = 0, x1 = 0, x2 = 0, x3 = 0;
        if (lane == 0) {
            const float* xr = X2 + (size_t)t * (4 * NH2) + uu;
            x0 = xr[0]; x1 = xr[NH2]; x2 = xr[2 * NH2]; x3 = xr[3 * NH2];
        }
        float a0 = 0, a1 = 0, a2 = 0, a3 = 0;
#pragma unroll
        for (int j = 0; j < 8; ++j) {
            float4 hv = *(const float4*)(hl + j * 256 + lane * 4);
            a0 = fmaf(wv[0][j*4+0], hv.x, a0); a0 = fmaf(wv[0][j*4+1], hv.y, a0);
            a0 = fmaf(wv[0][j*4+2], hv.z, a0); a0 = fmaf(wv[0][j*4+3], hv.w, a0);
            a1 = fmaf(wv[1][j*4+0], hv.x, a1); a1 = fmaf(wv[1][j*4+1], hv.y, a1);
            a1 = fmaf(wv[1][j*4+2], hv.z, a1); a1 = fmaf(wv[1][j*4+3], hv.w, a1);
            a2 = fmaf(wv[2][j*4+0], hv.x, a2); a2 = fmaf(wv[2][j*4+1], hv.y, a2);
            a2 = fmaf(wv[2][j*4+2], hv.z, a2); a2 = fmaf(wv[2][j*4+3], hv.w, a2);
            a3 = fmaf(wv[3][j*4+0], hv.x, a3); a3 = fmaf(wv[3][j*4+1], hv.y, a3);
            a3 = fmaf(wv[3][j*4+2], hv.z, a3); a3 = fmaf(wv[3][j*4+3], hv.w, a3);
        }
#pragma unroll
        for (int m = 32; m > 0; m >>= 1) {
            a0 += __shfl_xor(a0, m, 64); a1 += __shfl_xor(a1, m, 64);
            a2 += __shfl_xor(a2, m, 64); a3 += __shfl_xor(a3, m, 64);
        }
        if (lane == 0) {
            float gi = a0 + x0, gf = a1 + x1, gg = a2 + x2, go = a3 + x3;
            float cn = sigm(gf) * creg + sigm(gi) * tanh_f(gg);
            float hn = sigm(go) * tanh_f(cn);
            creg = cn;
            stf_agent(h2 + ((t + 1) & 1) * NH2 + uu, hn);   // coherent write-through
            PH[(size_t)t * NH2 + uu] = hn;
        }
        if (t < PSEQ - 1) {
            barrier3(syncg, wg, 16, 16, t);   // 256 = 16 x 16
            // stage next h: 4 coherent dword loads per thread -> LDS
            const float* hb = h2 + ((t + 1) & 1) * NH2 + tid * 4;
            float4 hv;
            hv.x = ldf_agent(hb + 0);
            hv.y = ldf_agent(hb + 1);
            hv.z = ldf_agent(hb + 2);
            hv.w = ldf_agent(hb + 3);
            *(float4*)(hl + tid * 4) = hv;
            __syncthreads();
        }
    }
}

// ---------------- column sum of S -> SSUM ----------------
__global__ void __launch_bounds__(256) k_colsum(const float* __restrict__ S, float* __restrict__ out)
{
    const int j = blockIdx.x * 256 + threadIdx.x;
    float a = 0.f;
    for (int t = 0; t < PSEQ; ++t) a += S[(size_t)t * NH2 + j];
    out[j] = a;
}

// ---------------- matvec: vout[r] = W[r]·vin + bscale*b[r] ----------------
__global__ void __launch_bounds__(256) k_mv(
    const float* __restrict__ W, const float* __restrict__ b, float bscale,
    const float* __restrict__ vin, float* __restrict__ vout)
{
    __shared__ float v[NH2];
    for (int i = threadIdx.x; i < NH2; i += 256) v[i] = vin[i];
    __syncthreads();
    const int r = blockIdx.x * 256 + threadIdx.x;
    const float4* wr = (const float4*)(W + (size_t)r * NH2);
    float a0 = 0, a1 = 0, a2 = 0, a3 = 0;
    for (int k4 = 0; k4 < NH2 / 4; ++k4) {
        float4 w4 = wr[k4];
        float4 x4 = *(const float4*)(&v[k4 * 4]);
        a0 = fmaf(w4.x, x4.x, a0); a1 = fmaf(w4.y, x4.y, a1);
        a2 = fmaf(w4.z, x4.z, a2); a3 = fmaf(w4.w, x4.w, a3);
    }
    vout[r] = (a0 + a1) + (a2 + a3) + bscale * b[r];
}

extern "C" void kernel_launch(void* const* d_in, const int* in_sizes, int n_in,
                              void* d_out, int out_size, void* d_ws, size_t ws_size,
                              hipStream_t stream)
{
    const float* sent   = (const float*)d_in[0];
    const float* action = (const float*)d_in[1];
    const int*   apos   = (const int*)  d_in[2];
    const float* Wih1   = (const float*)d_in[3];
    const float* Whh1   = (const float*)d_in[4];
    const float* bih1   = (const float*)d_in[5];
    const float* bhh1   = (const float*)d_in[6];
    const float* W1     = (const float*)d_in[7];
    const float* b1     = (const float*)d_in[8];
    const float* Wih2   = (const float*)d_in[9];
    const float* Whh2   = (const float*)d_in[10];
    const float* bih2   = (const float*)d_in[11];
    const float* bhh2   = (const float*)d_in[12];
    const float* W2     = (const float*)d_in[13];
    const float* b2     = (const float*)d_in[14];
    const float* ipw    = (const float*)d_in[15];
    const float* ipb    = (const float*)d_in[16];
    const float* opw    = (const float*)d_in[17];
    const float* opb    = (const float*)d_in[18];

    char* ws = (char*)d_ws;
    float*          X1   = (float*)(ws + OFF_X1);
    unsigned short* HBF  = (unsigned short*)(ws + OFF_HBF);
    float*          EMB  = (float*)(ws + OFF_EMB);
    float*          EMB2 = (float*)(ws + OFF_EMB2);
    float*          X2   = (float*)(ws + OFF_X2);
    float*          PH   = (float*)(ws + OFF_PH);
    float*          S    = (float*)(ws + OFF_S);
    float*          H2   = (float*)(ws + OFF_H2);
    float*          SSUM = (float*)(ws + OFF_SSUM);
    float*          TMP  = (float*)(ws + OFF_TMP);
    int*            META = (int*)  (ws + OFF_META);
    int*            SYNC = (int*)  (ws + OFF_SYNC);

    // re-zero stateful buffers every call (graph replays)
    hipMemsetAsync(ws + OFF_HBF, 0, SZ_HBF, stream);
    hipMemsetAsync(ws + OFF_SYNC, 0, SZ_SYNC, stream);

    hipFuncSetAttribute((const void*)k_s1, hipFuncAttributeMaxDynamicSharedMemorySize, S1_LDS);

    // X1 = sent @ Wih1.T + bih1 + bhh1   (2048 x 2400, K=300)
    gemm_rows<32><<<dim3(10, 64), 256, 0, stream>>>(sent, TSEQ, DIN, Wih1, 4 * NH1, bih1, bhh1, X1, 0);
    // segment starts / lengths / sort
    k_start<<<1, 256, 0, stream>>>(action, apos, META);
    // stage-1 chains (MFMA) -> EMB
    k_s1<<<75, 512, S1_LDS, stream>>>(X1, Whh1, META, HBF, EMB, SYNC);
    // EMB2 = tanh(EMB @ W1.T + b1)       (256 x 600, K=600)
    gemm_rows<8><<<dim3(3, 32), 256, 0, stream>>>(EMB, PSEQ, NH1, W1, NH1, b1, nullptr, EMB2, 1);
    // X2 = EMB2 @ Wih2.T + bih2 + bhh2   (256 x 8192, K=600)
    gemm_rows<32><<<dim3(32, 8), 256, 0, stream>>>(EMB2, PSEQ, NH1, Wih2, 4 * NH2, bih2, bhh2, X2, 0);
    // stage-2 LSTM -> PH (256 x 2048)
    k_s2<<<256, 512, 0, stream>>>(X2, Whh2, H2, PH, SYNC);
    // S = tanh(PH @ W2.T + b2)           (256 x 2048, K=2048)
    gemm_rows<8><<<dim3(8, 32), 256, 0, stream>>>(PH, PSEQ, NH2, W2, NH2, b2, nullptr, S, 1);
    // SSUM = column sums of S
    k_colsum<<<8, 256, 0, stream>>>(S, SSUM);
    // attention collapse: out = (SSUM @ Wv.T + 256*bv) @ Wo.T + 256*bo
    k_mv<<<8, 256, 0, stream>>>(ipw + (size_t)4096 * NH2, ipb + 4096, 256.f, SSUM, TMP);
    k_mv<<<8, 256, 0, stream>>>(opw, opb, 256.f, TMP, (float*)d_out);
}

// Round 5
// 2245.479 us; speedup vs baseline: 2.3292x; 1.0003x over previous
//
#include <hip/hip_runtime.h>
#include <cstdint>
#include <cstddef>

// ---------------- problem constants ----------------
static constexpr int TSEQ = 2048;   // T
static constexpr int PSEQ = 256;    // P
static constexpr int DIN  = 300;
static constexpr int NH1  = 600;
static constexpr int NH2  = 2048;

// ---------------- ws layout (bytes) ----------------
static constexpr size_t OFF_X1   = 0;                                   // [2048][2400] f32
static constexpr size_t SZ_X1    = (size_t)TSEQ * 4 * NH1 * 4;
static constexpr size_t OFF_HBF  = OFF_X1 + SZ_X1;                      // [2][256][600] bf16 dbl-buf
static constexpr size_t SZ_HBF   = 2ull * PSEQ * NH1 * 2;
static constexpr size_t OFF_EMB  = OFF_HBF + SZ_HBF;                    // [256][600] f32
static constexpr size_t SZ_EMB   = (size_t)PSEQ * NH1 * 4;
static constexpr size_t OFF_EMB2 = OFF_EMB + SZ_EMB;                    // [256][600] f32
static constexpr size_t SZ_EMB2  = (size_t)PSEQ * NH1 * 4;
static constexpr size_t OFF_X2   = OFF_EMB2 + SZ_EMB2;                  // [256][8192] f32
static constexpr size_t SZ_X2    = (size_t)PSEQ * 4 * NH2 * 4;
static constexpr size_t OFF_PH   = OFF_X2 + SZ_X2;                      // [256][2048] f32
static constexpr size_t SZ_PH    = (size_t)PSEQ * NH2 * 4;
static constexpr size_t OFF_S    = OFF_PH + SZ_PH;                      // [256][2048] f32
static constexpr size_t SZ_S     = (size_t)PSEQ * NH2 * 4;
static constexpr size_t OFF_H2   = OFF_S + SZ_S;                        // [2][2048] f32
static constexpr size_t SZ_H2    = 2ull * NH2 * 4;
static constexpr size_t OFF_SSUM = OFF_H2 + SZ_H2;                      // 2048 f32
static constexpr size_t OFF_TMP  = OFF_SSUM + 8192;                     // 2048 f32
static constexpr size_t OFF_META = OFF_TMP + 8192;                      // ints: st[256] L[256] ord[256] Ls[256] lmax
static constexpr size_t OFF_SYNC = OFF_META + 8192;                     // barrier counters (2 regions x 2048 ints)
static constexpr size_t SZ_SYNC  = 16384;

// k_s1 dynamic LDS: W 32x600 bf16 + h 64x600 bf16 + g 32x68 f32 + c 256x8 f32 + meta 3x256 int
static constexpr int S1_LDS = (32*600 + 64*600) * 2 + 32*68*4 + 256*8*4 + 3*256*4;   // 135168

#define DEVI __device__ __forceinline__

typedef __attribute__((ext_vector_type(8))) short short8v;   // 8 bf16 (4 VGPRs)
typedef __attribute__((ext_vector_type(4))) float f32x4;     // MFMA acc

DEVI float sigm(float x) {
    x = fminf(30.f, fmaxf(-30.f, x));
    return 1.f / (1.f + __expf(-x));
}
DEVI float tanh_f(float x) {
    x = fminf(15.f, fmaxf(-15.f, x));
    float t = __expf(2.f * x);
    return (t - 1.f) / (t + 1.f);
}
DEVI uint16_t f2bf(float f) {  // RNE fp32->bf16
    uint32_t u = __float_as_uint(f);
    return (uint16_t)((u + 0x7fffu + ((u >> 16) & 1u)) >> 16);
}

DEVI int ld_agent(const int* p) {
    return __hip_atomic_load(p, __ATOMIC_RELAXED, __HIP_MEMORY_SCOPE_AGENT);
}
DEVI unsigned int ldu_agent(const unsigned int* p) {
    return __hip_atomic_load(p, __ATOMIC_RELAXED, __HIP_MEMORY_SCOPE_AGENT);
}
DEVI float ldf_agent(const float* p) {
    return __hip_atomic_load(p, __ATOMIC_RELAXED, __HIP_MEMORY_SCOPE_AGENT);
}
DEVI void stu_agent(unsigned int* p, unsigned int v) {
    __hip_atomic_store(p, v, __ATOMIC_RELAXED, __HIP_MEMORY_SCOPE_AGENT);
}
DEVI void stf_agent(float* p, float v) {
    __hip_atomic_store(p, v, __ATOMIC_RELAXED, __HIP_MEMORY_SCOPE_AGENT);
}

// ---- fence-free device barrier: relaxed atomics only; data moves via sc-flagged ops ----
// Correctness: writers' sc-stores drained by the __syncthreads (per-wave vmcnt(0)) BEFORE
// the arrive-RMW; arrive -> root -> go all execute at the device coherence point; readers'
// sc-loads also read the coherence point. No buffer_wbl2 / buffer_inv anywhere.
// area ints: arrive[b] @ b*32 ; root @ 600 ; go[b] @ 1024 + b*32.
DEVI void barrier3(int* area, int wgid, int nb, int pb, int phase) {
    __syncthreads();   // all waves' outstanding global (sc) stores retired
    if (threadIdx.x == 0) {
        const int b = wgid % nb;
        int old = __hip_atomic_fetch_add(&area[b * 32], 1,
                                         __ATOMIC_RELAXED, __HIP_MEMORY_SCOPE_AGENT);
        if ((old % pb) == pb - 1) {
            int old2 = __hip_atomic_fetch_add(&area[600], 1,
                                              __ATOMIC_RELAXED, __HIP_MEMORY_SCOPE_AGENT);
            if ((old2 % nb) == nb - 1) {           // last arriver overall -> releaser
                for (int i = 0; i < nb; ++i)
                    stu_agent((unsigned int*)&area[1024 + i * 32], (unsigned int)(phase + 1));
            }
        }
        while (ld_agent(&area[1024 + b * 32]) < phase + 1)
            __builtin_amdgcn_s_sleep(1);
    }
    __syncthreads();
}

// ---------------- generic fp32 GEMM: out[t][r] = act(X[t]·W[r] + bA[r] (+ bB[r])) ----------------
template <int TBLK>
__global__ void __launch_bounds__(256) gemm_rows(
    const float* __restrict__ X, int T, int K,
    const float* __restrict__ W, int R,
    const float* __restrict__ bA, const float* __restrict__ bB,
    float* __restrict__ out, int act)
{
    __shared__ float xt[TBLK][448];
    const int r  = blockIdx.x * 256 + threadIdx.x;
    const int t0 = blockIdx.y * TBLK;
    float acc[TBLK];
#pragma unroll
    for (int i = 0; i < TBLK; ++i) acc[i] = 0.f;

    for (int kc0 = 0; kc0 < K; kc0 += 448) {
        const int kc  = (K - kc0 < 448) ? (K - kc0) : 448;
        const int kc4 = kc >> 2;
        __syncthreads();
        for (int idx = threadIdx.x; idx < TBLK * kc4; idx += 256) {
            int tt = idx / kc4, kk = idx - tt * kc4;
            float4 v = make_float4(0.f, 0.f, 0.f, 0.f);
            if (t0 + tt < T)
                v = *(const float4*)(X + (size_t)(t0 + tt) * K + kc0 + kk * 4);
            *(float4*)(&xt[tt][kk * 4]) = v;
        }
        __syncthreads();
        if (r < R) {
            const float4* wr = (const float4*)(W + (size_t)r * K + kc0);
            for (int k4 = 0; k4 < kc4; ++k4) {
                float4 w4 = wr[k4];
#pragma unroll
                for (int tt = 0; tt < TBLK; ++tt) {
                    float4 x4 = *(const float4*)(&xt[tt][k4 * 4]);
                    acc[tt] = fmaf(w4.x, x4.x, acc[tt]);
                    acc[tt] = fmaf(w4.y, x4.y, acc[tt]);
                    acc[tt] = fmaf(w4.z, x4.z, acc[tt]);
                    acc[tt] = fmaf(w4.w, x4.w, acc[tt]);
                }
            }
        }
    }
    if (r < R) {
        float bb = bA[r] + (bB ? bB[r] : 0.f);
#pragma unroll
        for (int tt = 0; tt < TBLK; ++tt) {
            if (t0 + tt < T) {
                float v = acc[tt] + bb;
                if (act) v = tanh_f(v);
                out[(size_t)(t0 + tt) * R + r] = v;
            }
        }
    }
}

// ---------------- segment starts + length-sort (1 block, 256 threads) ----------------
__global__ void __launch_bounds__(256) k_start(
    const float* __restrict__ action, const int* __restrict__ apos, int* __restrict__ meta)
{
    __shared__ int Lsh[256];
    const int p = threadIdx.x;
    const int pos = apos[p];
    int u = pos;
    while (u > 0 && action[u - 1] == 0.0f) --u;
    const int L = pos - u + 1;
    meta[p] = u;
    meta[256 + p] = L;
    Lsh[p] = L;
    __syncthreads();
    int rank = 0;
    for (int q = 0; q < 256; ++q) {
        int Lq = Lsh[q];
        if (Lq > L || (Lq == L && q < p)) ++rank;
    }
    meta[512 + rank] = p;
    meta[768 + rank] = L;
    if (rank == 0) meta[1024] = L;
}

// ---------------- stage-1 LSTM via MFMA: 75 wgs x 8 units, chains lockstep ----------------
__global__ void __launch_bounds__(512) k_s1(
    const float* __restrict__ X1, const float* __restrict__ Whh1,
    const int* __restrict__ meta,
    unsigned short* __restrict__ Hbf, float* __restrict__ EMB,
    int* __restrict__ sync)
{
    extern __shared__ char smem[];
    unsigned short* wl = (unsigned short*)smem;            // [32][600] bf16
    unsigned short* hl = wl + 32 * 600;                    // [64][600] bf16
    float* glds = (float*)(hl + 64 * 600);                 // [32][68] gates
    float* clds = glds + 32 * 68;                          // [256][8] c-state
    int* ordC  = (int*)(clds + 256 * 8);
    int* ordST = ordC + 256;
    int* ordL  = ordST + 256;

    const int wg  = blockIdx.x;        // 0..74, owns units u0..u0+7
    const int u0  = wg * 8;
    const int tid = threadIdx.x;
    const int lane = tid & 63;
    const int w  = tid >> 6;
    const int ct = w & 3, rt = w >> 2;

    for (int idx = tid; idx < 32 * 150; idx += 512) {
        int rr = idx / 150, j = idx - rr * 150;
        int gamma = rr >> 3, u = rr & 7;
        float4 v = *(const float4*)(Whh1 + (size_t)(gamma * 600 + u0 + u) * 600 + j * 4);
        ushort4 pk = make_ushort4(f2bf(v.x), f2bf(v.y), f2bf(v.z), f2bf(v.w));
        *(ushort4*)(wl + rr * 600 + j * 4) = pk;
    }
    if (tid < 256) {
        int p = meta[512 + tid];
        ordC[tid]  = p;
        ordST[tid] = meta[p];
        ordL[tid]  = meta[256 + p];
    }
    for (int idx = tid; idx < 2048; idx += 512) clds[idx] = 0.f;
    __syncthreads();

    const int lmax = ordL[0];
    int A = 256;

    for (int k = 0; k < lmax; ++k) {
        while (A > 0 && ordL[A - 1] <= k) --A;
        const int rb = k & 1;
        const unsigned short* Hr = Hbf + (size_t)rb * PSEQ * NH1;
        unsigned short*       Hw = Hbf + (size_t)(rb ^ 1) * PSEQ * NH1;
        const int ng = (A + 63) >> 6;

        for (int g = 0; g < ng; ++g) {
            const int sc  = (A - g * 64 < 64) ? (A - g * 64) : 64;
            const int nst = (sc + 15) & ~15;
            __syncthreads();
            // stage h (bf16) via coherent uint loads (2 bf16 per load)
            for (int idx = tid; idx < nst * 300; idx += 512) {
                int ci = idx / 300, j2 = idx - ci * 300;
                int ch = ordC[g * 64 + ci];
                unsigned int v = ldu_agent((const unsigned int*)(Hr + (size_t)ch * 600) + j2);
                *((unsigned int*)(hl + (size_t)ci * 600) + j2) = v;
            }
            __syncthreads();

            // epilogue-role prefetch: X1 gate values + meta (independent of h)
            const int s_loc = tid >> 3, eu = tid & 7;
            const bool ep = (s_loc < sc);
            int ch = 0, st = 0, L = 0;
            float xv0 = 0, xv1 = 0, xv2 = 0, xv3 = 0;
            if (ep) {
                ch = ordC[g * 64 + s_loc];
                st = ordST[g * 64 + s_loc];
                L  = ordL[g * 64 + s_loc];
                const float* xr = X1 + (size_t)(st + k) * 2400 + u0 + eu;
                xv0 = xr[0]; xv1 = xr[600]; xv2 = xr[1200]; xv3 = xr[1800];
            }

            // MFMA: D[chain][row] += h · W^T
            if (ct * 16 < sc) {
                f32x4 acc = {0.f, 0.f, 0.f, 0.f};
                const int kg = lane >> 4;
                const short* ha = (const short*)hl + (ct * 16 + (lane & 15)) * 600;
                const short* wb = (const short*)wl + (rt * 16 + (lane & 15)) * 600;
#pragma unroll
                for (int kt = 0; kt < 19; ++kt) {
                    int k0 = kt * 32 + kg * 8;
                    short8v af = {0, 0, 0, 0, 0, 0, 0, 0};
                    short8v bf = {0, 0, 0, 0, 0, 0, 0, 0};
                    if (k0 < 600) {
                        af = *(const short8v*)(ha + k0);
                        bf = *(const short8v*)(wb + k0);
                    }
                    acc = __builtin_amdgcn_mfma_f32_16x16x32_bf16(af, bf, acc, 0, 0, 0);
                }
                const int brow = rt * 16 + (lane & 15);
                const int ch0  = ct * 16 + ((lane >> 4) << 2);
                *(f32x4*)(glds + brow * 68 + ch0) = acc;
            }
            __syncthreads();

            // gate epilogue: compute unconditionally (safe garbage), guard stores with ep
            {
                float gi = glds[(0 * 8 + eu) * 68 + s_loc] + xv0;
                float gf = glds[(1 * 8 + eu) * 68 + s_loc] + xv1;
                float gg = glds[(2 * 8 + eu) * 68 + s_loc] + xv2;
                float go = glds[(3 * 8 + eu) * 68 + s_loc] + xv3;
                float co = clds[ch * 8 + eu];
                float cn = sigm(gf) * co + sigm(gi) * tanh_f(gg);
                float hn = sigm(go) * tanh_f(cn);
                if (ep) clds[ch * 8 + eu] = cn;
                unsigned int pk = (unsigned int)f2bf(hn);
                unsigned int hi = __shfl_down(pk, 1, 64);
                if (ep && (eu & 1) == 0)
                    stu_agent((unsigned int*)(Hw + (size_t)ch * 600 + u0 + eu), pk | (hi << 16));
                if (ep && k == L - 1)
                    EMB[(size_t)ch * 600 + u0 + eu] = hn;
            }
        }
        if (k < lmax - 1) barrier3(sync, wg, 15, 5, k);   // 75 = 15 buckets x 5
    }
}

// ---------------- stage-2 LSTM: 256 wgs x 8 units; 512 thr; wave w owns unit w ----------------
__global__ void __launch_bounds__(512) k_s2(
    const float* __restrict__ X2, const float* __restrict__ Whh2,
    float* __restrict__ h2, float* __restrict__ PH, int* __restrict__ sync)
{
    __shared__ float hl[NH2];
    const int wg   = blockIdx.x;
    const int tid  = threadIdx.x;
    const int lane = tid & 63;
    const int w    = tid >> 6;         // wave = unit 0..7
    const int uu   = wg * 8 + w;
    int* syncg = sync + 2048;

    // preload 4 gate rows fp32 into VGPRs: wv[g][j*4+c] = Whh2[g*2048+uu][j*256+lane*4+c]
    float wv[4][32];
#pragma unroll
    for (int g = 0; g < 4; ++g) {
        const float* rp = Whh2 + ((size_t)(g * NH2 + uu)) * NH2 + lane * 4;
#pragma unroll
        for (int j = 0; j < 8; ++j) {
            float4 a = *(const float4*)(rp + j * 256);
            wv[g][j * 4 + 0] = a.x; wv[g][j * 4 + 1] = a.y;
            wv[g][j * 4 + 2] = a.z; wv[g][j * 4 + 3] = a.w;
        }
    }
    *(float4*)(hl + tid * 4) = make_float4(0.f, 0.f, 0.f, 0.f);
    float creg = 0.f;
    __syncthreads();

    for (int t = 0; t < PSEQ; ++t) {
        // prefetch x gate values (lane0 of each wave), independent of h
        float x0 = 0, x1 = 0, x2 = 0, x3 = 0;
        if (lane == 0) {
            const float* xr = X2 + (size_t)t * (4 * NH2) + uu;
            x0 = xr[0]; x1 = xr[NH2]; x2 = xr[2 * NH2]; x3 = xr[3 * NH2];
        }
        float a0 = 0, a1 = 0, a2 = 0, a3 = 0;
#pragma unroll
        for (int j = 0; j < 8; ++j) {
            float4 hv = *(const float4*)(hl + j * 256 + lane * 4);
            a0 = fmaf(wv[0][j*4+0], hv.x, a0); a0 = fmaf(wv[0][j*4+1], hv.y, a0);
            a0 = fmaf(wv[0][j*4+2], hv.z, a0); a0 = fmaf(wv[0][j*4+3], hv.w, a0);
            a1 = fmaf(wv[1][j*4+0], hv.x, a1); a1 = fmaf(wv[1][j*4+1], hv.y, a1);
            a1 = fmaf(wv[1][j*4+2], hv.z, a1); a1 = fmaf(wv[1][j*4+3], hv.w, a1);
            a2 = fmaf(wv[2][j*4+0], hv.x, a2); a2 = fmaf(wv[2][j*4+1], hv.y, a2);
            a2 = fmaf(wv[2][j*4+2], hv.z, a2); a2 = fmaf(wv[2][j*4+3], hv.w, a2);
            a3 = fmaf(wv[3][j*4+0], hv.x, a3); a3 = fmaf(wv[3][j*4+1], hv.y, a3);
            a3 = fmaf(wv[3][j*4+2], hv.z, a3); a3 = fmaf(wv[3][j*4+3], hv.w, a3);
        }
#pragma unroll
        for (int m = 32; m > 0; m >>= 1) {
            a0 += __shfl_xor(a0, m, 64); a1 += __shfl_xor(a1, m, 64);
            a2 += __shfl_xor(a2, m, 64); a3 += __shfl_xor(a3, m, 64);
        }
        if (lane == 0) {
            float gi = a0 + x0, gf = a1 + x1, gg = a2 + x2, go = a3 + x3;
            float cn = sigm(gf) * creg + sigm(gi) * tanh_f(gg);
            float hn = sigm(go) * tanh_f(cn);
            creg = cn;
            stf_agent(h2 + ((t + 1) & 1) * NH2 + uu, hn);   // coherent write-through
            PH[(size_t)t * NH2 + uu] = hn;
        }
        if (t < PSEQ - 1) {
            barrier3(syncg, wg, 16, 16, t);   // 256 = 16 x 16
            // stage next h: 4 coherent dword loads per thread -> LDS
            const float* hb = h2 + ((t + 1) & 1) * NH2 + tid * 4;
            float4 hv;
            hv.x = ldf_agent(hb + 0);
            hv.y = ldf_agent(hb + 1);
            hv.z = ldf_agent(hb + 2);
            hv.w = ldf_agent(hb + 3);
            *(float4*)(hl + tid * 4) = hv;
            __syncthreads();
        }
    }
}

// ---------------- column sum of S -> SSUM ----------------
__global__ void __launch_bounds__(256) k_colsum(const float* __restrict__ S, float* __restrict__ out)
{
    const int j = blockIdx.x * 256 + threadIdx.x;
    float a = 0.f;
    for (int t = 0; t < PSEQ; ++t) a += S[(size_t)t * NH2 + j];
    out[j] = a;
}

// ---------------- matvec: vout[r] = W[r]·vin + bscale*b[r] ----------------
__global__ void __launch_bounds__(256) k_mv(
    const float* __restrict__ W, const float* __restrict__ b, float bscale,
    const float* __restrict__ vin, float* __restrict__ vout)
{
    __shared__ float v[NH2];
    for (int i = threadIdx.x; i < NH2; i += 256) v[i] = vin[i];
    __syncthreads();
    const int r = blockIdx.x * 256 + threadIdx.x;
    const float4* wr = (const float4*)(W + (size_t)r * NH2);
    float a0 = 0, a1 = 0, a2 = 0, a3 = 0;
    for (int k4 = 0; k4 < NH2 / 4; ++k4) {
        float4 w4 = wr[k4];
        float4 x4 = *(const float4*)(&v[k4 * 4]);
        a0 = fmaf(w4.x, x4.x, a0); a1 = fmaf(w4.y, x4.y, a1);
        a2 = fmaf(w4.z, x4.z, a2); a3 = fmaf(w4.w, x4.w, a3);
    }
    vout[r] = (a0 + a1) + (a2 + a3) + bscale * b[r];
}

extern "C" void kernel_launch(void* const* d_in, const int* in_sizes, int n_in,
                              void* d_out, int out_size, void* d_ws, size_t ws_size,
                              hipStream_t stream)
{
    const float* sent   = (const float*)d_in[0];
    const float* action = (const float*)d_in[1];
    const int*   apos   = (const int*)  d_in[2];
    const float* Wih1   = (const float*)d_in[3];
    const float* Whh1   = (const float*)d_in[4];
    const float* bih1   = (const float*)d_in[5];
    const float* bhh1   = (const float*)d_in[6];
    const float* W1     = (const float*)d_in[7];
    const float* b1     = (const float*)d_in[8];
    const float* Wih2   = (const float*)d_in[9];
    const float* Whh2   = (const float*)d_in[10];
    const float* bih2   = (const float*)d_in[11];
    const float* bhh2   = (const float*)d_in[12];
    const float* W2     = (const float*)d_in[13];
    const float* b2     = (const float*)d_in[14];
    const float* ipw    = (const float*)d_in[15];
    const float* ipb    = (const float*)d_in[16];
    const float* opw    = (const float*)d_in[17];
    const float* opb    = (const float*)d_in[18];

    char* ws = (char*)d_ws;
    float*          X1   = (float*)(ws + OFF_X1);
    unsigned short* HBF  = (unsigned short*)(ws + OFF_HBF);
    float*          EMB  = (float*)(ws + OFF_EMB);
    float*          EMB2 = (float*)(ws + OFF_EMB2);
    float*          X2   = (float*)(ws + OFF_X2);
    float*          PH   = (float*)(ws + OFF_PH);
    float*          S    = (float*)(ws + OFF_S);
    float*          H2   = (float*)(ws + OFF_H2);
    float*          SSUM = (float*)(ws + OFF_SSUM);
    float*          TMP  = (float*)(ws + OFF_TMP);
    int*            META = (int*)  (ws + OFF_META);
    int*            SYNC = (int*)  (ws + OFF_SYNC);

    // re-zero stateful buffers every call (graph replays)
    hipMemsetAsync(ws + OFF_HBF, 0, SZ_HBF, stream);
    hipMemsetAsync(ws + OFF_SYNC, 0, SZ_SYNC, stream);

    hipFuncSetAttribute((const void*)k_s1, hipFuncAttributeMaxDynamicSharedMemorySize, S1_LDS);

    // X1 = sent @ Wih1.T + bih1 + bhh1   (2048 x 2400, K=300)
    gemm_rows<32><<<dim3(10, 64), 256, 0, stream>>>(sent, TSEQ, DIN, Wih1, 4 * NH1, bih1, bhh1, X1, 0);
    // segment starts / lengths / sort
    k_start<<<1, 256, 0, stream>>>(action, apos, META);
    // stage-1 chains (MFMA) -> EMB
    k_s1<<<75, 512, S1_LDS, stream>>>(X1, Whh1, META, HBF, EMB, SYNC);
    // EMB2 = tanh(EMB @ W1.T + b1)       (256 x 600, K=600)
    gemm_rows<8><<<dim3(3, 32), 256, 0, stream>>>(EMB, PSEQ, NH1, W1, NH1, b1, nullptr, EMB2, 1);
    // X2 = EMB2 @ Wih2.T + bih2 + bhh2   (256 x 8192, K=600)
    gemm_rows<32><<<dim3(32, 8), 256, 0, stream>>>(EMB2, PSEQ, NH1, Wih2, 4 * NH2, bih2, bhh2, X2, 0);
    // stage-2 LSTM -> PH (256 x 2048)
    k_s2<<<256, 512, 0, stream>>>(X2, Whh2, H2, PH, SYNC);
    // S = tanh(PH @ W2.T + b2)           (256 x 2048, K=2048)
    gemm_rows<8><<<dim3(8, 32), 256, 0, stream>>>(PH, PSEQ, NH2, W2, NH2, b2, nullptr, S, 1);
    // SSUM = column sums of S
    k_colsum<<<8, 256, 0, stream>>>(S, SSUM);
    // attention collapse: out = (SSUM @ Wv.T + 256*bv) @ Wo.T + 256*bo
    k_mv<<<8, 256, 0, stream>>>(ipw + (size_t)4096 * NH2, ipb + 4096, 256.f, SSUM, TMP);
    k_mv<<<8, 256, 0, stream>>>(opw, opb, 256.f, TMP, (float*)d_out);
}

// Round 6
// 2243.435 us; speedup vs baseline: 2.3314x; 1.0009x over previous
//
#include <hip/hip_runtime.h>
#include <cstdint>
#include <cstddef>

// ---------------- problem constants ----------------
static constexpr int TSEQ = 2048;   // T
static constexpr int PSEQ = 256;    // P
static constexpr int DIN  = 300;
static constexpr int NH1  = 600;
static constexpr int NH2  = 2048;

// ---------------- ws layout (bytes) ----------------
static constexpr size_t OFF_X1   = 0;                                   // [2048][2400] f32
static constexpr size_t SZ_X1    = (size_t)TSEQ * 4 * NH1 * 4;
static constexpr size_t OFF_HBF  = OFF_X1 + SZ_X1;                      // [2][256][600] bf16 dbl-buf
static constexpr size_t SZ_HBF   = 2ull * PSEQ * NH1 * 2;
static constexpr size_t OFF_EMB  = OFF_HBF + SZ_HBF;                    // [256][600] f32
static constexpr size_t SZ_EMB   = (size_t)PSEQ * NH1 * 4;
static constexpr size_t OFF_EMB2 = OFF_EMB + SZ_EMB;                    // [256][600] f32
static constexpr size_t SZ_EMB2  = (size_t)PSEQ * NH1 * 4;
static constexpr size_t OFF_X2   = OFF_EMB2 + SZ_EMB2;                  // [256][8192] f32
static constexpr size_t SZ_X2    = (size_t)PSEQ * 4 * NH2 * 4;
static constexpr size_t OFF_PH   = OFF_X2 + SZ_X2;                      // [256][2048] f32
static constexpr size_t SZ_PH    = (size_t)PSEQ * NH2 * 4;
static constexpr size_t OFF_S    = OFF_PH + SZ_PH;                      // [256][2048] f32
static constexpr size_t SZ_S     = (size_t)PSEQ * NH2 * 4;
static constexpr size_t OFF_H2   = OFF_S + SZ_S;                        // [2][2048] f32
static constexpr size_t SZ_H2    = 2ull * NH2 * 4;
static constexpr size_t OFF_SSUM = OFF_H2 + SZ_H2;                      // 2048 f32
static constexpr size_t OFF_TMP  = OFF_SSUM + 8192;                     // 2048 f32
static constexpr size_t OFF_META = OFF_TMP + 8192;                      // ints: st[256] L[256] ord[256] Ls[256] lmax
static constexpr size_t OFF_SYNC = OFF_META + 8192;                     // barrier counters (2 regions x 2048 ints)
static constexpr size_t SZ_SYNC  = 16384;

// k_s1 dynamic LDS: W 32x600 bf16 + h 64x600 bf16 + g 32x68 f32 + c 256x8 f32 + meta 3x256 int
static constexpr int S1_LDS = (32*600 + 64*600) * 2 + 32*68*4 + 256*8*4 + 3*256*4;   // 135168

#define DEVI __device__ __forceinline__

typedef __attribute__((ext_vector_type(8))) short short8v;   // 8 bf16 (4 VGPRs)
typedef __attribute__((ext_vector_type(4))) float f32x4;     // MFMA acc

DEVI float sigm(float x) {
    x = fminf(30.f, fmaxf(-30.f, x));
    return 1.f / (1.f + __expf(-x));
}
DEVI float tanh_f(float x) {
    x = fminf(15.f, fmaxf(-15.f, x));
    float t = __expf(2.f * x);
    return (t - 1.f) / (t + 1.f);
}
DEVI uint16_t f2bf(float f) {  // RNE fp32->bf16
    uint32_t u = __float_as_uint(f);
    return (uint16_t)((u + 0x7fffu + ((u >> 16) & 1u)) >> 16);
}

DEVI int ld_agent(const int* p) {
    return __hip_atomic_load(p, __ATOMIC_RELAXED, __HIP_MEMORY_SCOPE_AGENT);
}
DEVI unsigned int ldu_agent(const unsigned int* p) {
    return __hip_atomic_load(p, __ATOMIC_RELAXED, __HIP_MEMORY_SCOPE_AGENT);
}
DEVI float ldf_agent(const float* p) {
    return __hip_atomic_load(p, __ATOMIC_RELAXED, __HIP_MEMORY_SCOPE_AGENT);
}
DEVI void stu_agent(unsigned int* p, unsigned int v) {
    __hip_atomic_store(p, v, __ATOMIC_RELAXED, __HIP_MEMORY_SCOPE_AGENT);
}
DEVI void stf_agent(float* p, float v) {
    __hip_atomic_store(p, v, __ATOMIC_RELAXED, __HIP_MEMORY_SCOPE_AGENT);
}

// ---- fence-free device barrier: relaxed atomics only; data moves via sc-flagged ops ----
// Correctness: writers' sc-stores drained by the __syncthreads (per-wave vmcnt(0)) BEFORE
// the arrive-RMW; arrive -> root -> go all execute at the device coherence point; readers'
// sc-loads also read the coherence point. No buffer_wbl2 / buffer_inv anywhere.
// area ints: arrive[b] @ b*32 ; root @ 600 ; go[b] @ 1024 + b*32.
DEVI void barrier3(int* area, int wgid, int nb, int pb, int phase) {
    __syncthreads();   // all waves' outstanding global (sc) stores retired
    if (threadIdx.x == 0) {
        const int b = wgid % nb;
        int old = __hip_atomic_fetch_add(&area[b * 32], 1,
                                         __ATOMIC_RELAXED, __HIP_MEMORY_SCOPE_AGENT);
        if ((old % pb) == pb - 1) {
            int old2 = __hip_atomic_fetch_add(&area[600], 1,
                                              __ATOMIC_RELAXED, __HIP_MEMORY_SCOPE_AGENT);
            if ((old2 % nb) == nb - 1) {           // last arriver overall -> releaser
                for (int i = 0; i < nb; ++i)
                    stu_agent((unsigned int*)&area[1024 + i * 32], (unsigned int)(phase + 1));
            }
        }
        while (ld_agent(&area[1024 + b * 32]) < phase + 1)
            __builtin_amdgcn_s_sleep(1);
    }
    __syncthreads();
}

// ---------------- generic fp32 GEMM: out[t][r] = act(X[t]·W[r] + bA[r] (+ bB[r])) ----------------
template <int TBLK>
__global__ void __launch_bounds__(256) gemm_rows(
    const float* __restrict__ X, int T, int K,
    const float* __restrict__ W, int R,
    const float* __restrict__ bA, const float* __restrict__ bB,
    float* __restrict__ out, int act)
{
    __shared__ float xt[TBLK][448];
    const int r  = blockIdx.x * 256 + threadIdx.x;
    const int t0 = blockIdx.y * TBLK;
    float acc[TBLK];
#pragma unroll
    for (int i = 0; i < TBLK; ++i) acc[i] = 0.f;

    for (int kc0 = 0; kc0 < K; kc0 += 448) {
        const int kc  = (K - kc0 < 448) ? (K - kc0) : 448;
        const int kc4 = kc >> 2;
        __syncthreads();
        for (int idx = threadIdx.x; idx < TBLK * kc4; idx += 256) {
            int tt = idx / kc4, kk = idx - tt * kc4;
            float4 v = make_float4(0.f, 0.f, 0.f, 0.f);
            if (t0 + tt < T)
                v = *(const float4*)(X + (size_t)(t0 + tt) * K + kc0 + kk * 4);
            *(float4*)(&xt[tt][kk * 4]) = v;
        }
        __syncthreads();
        if (r < R) {
            const float4* wr = (const float4*)(W + (size_t)r * K + kc0);
            for (int k4 = 0; k4 < kc4; ++k4) {
                float4 w4 = wr[k4];
#pragma unroll
                for (int tt = 0; tt < TBLK; ++tt) {
                    float4 x4 = *(const float4*)(&xt[tt][k4 * 4]);
                    acc[tt] = fmaf(w4.x, x4.x, acc[tt]);
                    acc[tt] = fmaf(w4.y, x4.y, acc[tt]);
                    acc[tt] = fmaf(w4.z, x4.z, acc[tt]);
                    acc[tt] = fmaf(w4.w, x4.w, acc[tt]);
                }
            }
        }
    }
    if (r < R) {
        float bb = bA[r] + (bB ? bB[r] : 0.f);
#pragma unroll
        for (int tt = 0; tt < TBLK; ++tt) {
            if (t0 + tt < T) {
                float v = acc[tt] + bb;
                if (act) v = tanh_f(v);
                out[(size_t)(t0 + tt) * R + r] = v;
            }
        }
    }
}

// ---------------- segment starts + length-sort (1 block, 256 threads) ----------------
__global__ void __launch_bounds__(256) k_start(
    const float* __restrict__ action, const int* __restrict__ apos, int* __restrict__ meta)
{
    __shared__ int Lsh[256];
    const int p = threadIdx.x;
    const int pos = apos[p];
    int u = pos;
    while (u > 0 && action[u - 1] == 0.0f) --u;
    const int L = pos - u + 1;
    meta[p] = u;
    meta[256 + p] = L;
    Lsh[p] = L;
    __syncthreads();
    int rank = 0;
    for (int q = 0; q < 256; ++q) {
        int Lq = Lsh[q];
        if (Lq > L || (Lq == L && q < p)) ++rank;
    }
    meta[512 + rank] = p;
    meta[768 + rank] = L;
    if (rank == 0) meta[1024] = L;
}

// ---------------- stage-1 LSTM via MFMA: 75 wgs x 8 units, chains lockstep ----------------
__global__ void __launch_bounds__(512) k_s1(
    const float* __restrict__ X1, const float* __restrict__ Whh1,
    const int* __restrict__ meta,
    unsigned short* __restrict__ Hbf, float* __restrict__ EMB,
    int* __restrict__ sync)
{
    extern __shared__ char smem[];
    unsigned short* wl = (unsigned short*)smem;            // [32][600] bf16
    unsigned short* hl = wl + 32 * 600;                    // [64][600] bf16
    float* glds = (float*)(hl + 64 * 600);                 // [32][68] gates
    float* clds = glds + 32 * 68;                          // [256][8] c-state
    int* ordC  = (int*)(clds + 256 * 8);
    int* ordST = ordC + 256;
    int* ordL  = ordST + 256;

    const int wg  = blockIdx.x;        // 0..74, owns units u0..u0+7
    const int u0  = wg * 8;
    const int tid = threadIdx.x;
    const int lane = tid & 63;
    const int w  = tid >> 6;
    const int ct = w & 3, rt = w >> 2;

    for (int idx = tid; idx < 32 * 150; idx += 512) {
        int rr = idx / 150, j = idx - rr * 150;
        int gamma = rr >> 3, u = rr & 7;
        float4 v = *(const float4*)(Whh1 + (size_t)(gamma * 600 + u0 + u) * 600 + j * 4);
        ushort4 pk = make_ushort4(f2bf(v.x), f2bf(v.y), f2bf(v.z), f2bf(v.w));
        *(ushort4*)(wl + rr * 600 + j * 4) = pk;
    }
    if (tid < 256) {
        int p = meta[512 + tid];
        ordC[tid]  = p;
        ordST[tid] = meta[p];
        ordL[tid]  = meta[256 + p];
    }
    for (int idx = tid; idx < 2048; idx += 512) clds[idx] = 0.f;
    __syncthreads();

    const int lmax = ordL[0];
    int A = 256;

    for (int k = 0; k < lmax; ++k) {
        while (A > 0 && ordL[A - 1] <= k) --A;
        const int rb = k & 1;
        const unsigned short* Hr = Hbf + (size_t)rb * PSEQ * NH1;
        unsigned short*       Hw = Hbf + (size_t)(rb ^ 1) * PSEQ * NH1;
        const int ng = (A + 63) >> 6;

        for (int g = 0; g < ng; ++g) {
            const int sc  = (A - g * 64 < 64) ? (A - g * 64) : 64;
            const int nst = (sc + 15) & ~15;
            __syncthreads();
            // stage h (bf16) via coherent uint loads (2 bf16 per load)
            for (int idx = tid; idx < nst * 300; idx += 512) {
                int ci = idx / 300, j2 = idx - ci * 300;
                int ch = ordC[g * 64 + ci];
                unsigned int v = ldu_agent((const unsigned int*)(Hr + (size_t)ch * 600) + j2);
                *((unsigned int*)(hl + (size_t)ci * 600) + j2) = v;
            }
            __syncthreads();

            // epilogue-role prefetch: X1 gate values + meta (independent of h)
            const int s_loc = tid >> 3, eu = tid & 7;
            const bool ep = (s_loc < sc);
            int ch = 0, st = 0, L = 0;
            float xv0 = 0, xv1 = 0, xv2 = 0, xv3 = 0;
            if (ep) {
                ch = ordC[g * 64 + s_loc];
                st = ordST[g * 64 + s_loc];
                L  = ordL[g * 64 + s_loc];
                const float* xr = X1 + (size_t)(st + k) * 2400 + u0 + eu;
                xv0 = xr[0]; xv1 = xr[600]; xv2 = xr[1200]; xv3 = xr[1800];
            }

            // MFMA: D[chain][row] += h · W^T
            if (ct * 16 < sc) {
                f32x4 acc = {0.f, 0.f, 0.f, 0.f};
                const int kg = lane >> 4;
                const short* ha = (const short*)hl + (ct * 16 + (lane & 15)) * 600;
                const short* wb = (const short*)wl + (rt * 16 + (lane & 15)) * 600;
#pragma unroll
                for (int kt = 0; kt < 19; ++kt) {
                    int k0 = kt * 32 + kg * 8;
                    short8v af = {0, 0, 0, 0, 0, 0, 0, 0};
                    short8v bf = {0, 0, 0, 0, 0, 0, 0, 0};
                    if (k0 < 600) {
                        af = *(const short8v*)(ha + k0);
                        bf = *(const short8v*)(wb + k0);
                    }
                    acc = __builtin_amdgcn_mfma_f32_16x16x32_bf16(af, bf, acc, 0, 0, 0);
                }
                const int brow = rt * 16 + (lane & 15);
                const int ch0  = ct * 16 + ((lane >> 4) << 2);
                *(f32x4*)(glds + brow * 68 + ch0) = acc;
            }
            __syncthreads();

            // gate epilogue: compute unconditionally (safe garbage), guard stores with ep
            {
                float gi = glds[(0 * 8 + eu) * 68 + s_loc] + xv0;
                float gf = glds[(1 * 8 + eu) * 68 + s_loc] + xv1;
                float gg = glds[(2 * 8 + eu) * 68 + s_loc] + xv2;
                float go = glds[(3 * 8 + eu) * 68 + s_loc] + xv3;
                float co = clds[ch * 8 + eu];
                float cn = sigm(gf) * co + sigm(gi) * tanh_f(gg);
                float hn = sigm(go) * tanh_f(cn);
                if (ep) clds[ch * 8 + eu] = cn;
                unsigned int pk = (unsigned int)f2bf(hn);
                unsigned int hi = __shfl_down(pk, 1, 64);
                if (ep && (eu & 1) == 0)
                    stu_agent((unsigned int*)(Hw + (size_t)ch * 600 + u0 + eu), pk | (hi << 16));
                if (ep && k == L - 1)
                    EMB[(size_t)ch * 600 + u0 + eu] = hn;
            }
        }
        if (k < lmax - 1) barrier3(sync, wg, 15, 5, k);   // 75 = 15 buckets x 5
    }
}

// ---------------- stage-2 LSTM: 256 wgs x 8 units; 512 thr; wave w owns unit w ----------------
__global__ void __launch_bounds__(512) k_s2(
    const float* __restrict__ X2, const float* __restrict__ Whh2,
    float* __restrict__ h2, float* __restrict__ PH, int* __restrict__ sync)
{
    __shared__ float hl[NH2];
    const int wg   = blockIdx.x;
    const int tid  = threadIdx.x;
    const int lane = tid & 63;
    const int w    = tid >> 6;         // wave = unit 0..7
    const int uu   = wg * 8 + w;
    int* syncg = sync + 2048;

    // preload 4 gate rows fp32 into VGPRs: wv[g][j*4+c] = Whh2[g*2048+uu][j*256+lane*4+c]
    float wv[4][32];
#pragma unroll
    for (int g = 0; g < 4; ++g) {
        const float* rp = Whh2 + ((size_t)(g * NH2 + uu)) * NH2 + lane * 4;
#pragma unroll
        for (int j = 0; j < 8; ++j) {
            float4 a = *(const float4*)(rp + j * 256);
            wv[g][j * 4 + 0] = a.x; wv[g][j * 4 + 1] = a.y;
            wv[g][j * 4 + 2] = a.z; wv[g][j * 4 + 3] = a.w;
        }
    }
    *(float4*)(hl + tid * 4) = make_float4(0.f, 0.f, 0.f, 0.f);
    float creg = 0.f;
    __syncthreads();

    for (int t = 0; t < PSEQ; ++t) {
        // prefetch x gate values (lane0 of each wave), independent of h
        float x0 = 0, x1 = 0, x2 = 0, x3 = 0;
        if (lane == 0) {
            const float* xr = X2 + (size_t)t * (4 * NH2) + uu;
            x0 = xr[0]; x1 = xr[NH2]; x2 = xr[2 * NH2]; x3 = xr[3 * NH2];
        }
        float a0 = 0, a1 = 0, a2 = 0, a3 = 0;
#pragma unroll
        for (int j = 0; j < 8; ++j) {
            float4 hv = *(const float4*)(hl + j * 256 + lane * 4);
            a0 = fmaf(wv[0][j*4+0], hv.x, a0); a0 = fmaf(wv[0][j*4+1], hv.y, a0);
            a0 = fmaf(wv[0][j*4+2], hv.z, a0); a0 = fmaf(wv[0][j*4+3], hv.w, a0);
            a1 = fmaf(wv[1][j*4+0], hv.x, a1); a1 = fmaf(wv[1][j*4+1], hv.y, a1);
            a1 = fmaf(wv[1][j*4+2], hv.z, a1); a1 = fmaf(wv[1][j*4+3], hv.w, a1);
            a2 = fmaf(wv[2][j*4+0], hv.x, a2); a2 = fmaf(wv[2][j*4+1], hv.y, a2);
            a2 = fmaf(wv[2][j*4+2], hv.z, a2); a2 = fmaf(wv[2][j*4+3], hv.w, a2);
            a3 = fmaf(wv[3][j*4+0], hv.x, a3); a3 = fmaf(wv[3][j*4+1], hv.y, a3);
            a3 = fmaf(wv[3][j*4+2], hv.z, a3); a3 = fmaf(wv[3][j*4+3], hv.w, a3);
        }
#pragma unroll
        for (int m = 32; m > 0; m >>= 1) {
            a0 += __shfl_xor(a0, m, 64); a1 += __shfl_xor(a1, m, 64);
            a2 += __shfl_xor(a2, m, 64); a3 += __shfl_xor(a3, m, 64);
        }
        if (lane == 0) {
            float gi = a0 + x0, gf = a1 + x1, gg = a2 + x2, go = a3 + x3;
            float cn = sigm(gf) * creg + sigm(gi) * tanh_f(gg);
            float hn = sigm(go) * tanh_f(cn);
            creg = cn;
            stf_agent(h2 + ((t + 1) & 1) * NH2 + uu, hn);   // coherent write-through
            PH[(size_t)t * NH2 + uu] = hn;
        }
        if (t < PSEQ - 1) {
            barrier3(syncg, wg, 16, 16, t);   // 256 = 16 x 16
            // stage next h: 4 coherent dword loads per thread -> LDS
            const float* hb = h2 + ((t + 1) & 1) * NH2 + tid * 4;
            float4 hv;
            hv.x = ldf_agent(hb + 0);
            hv.y = ldf_agent(hb + 1);
            hv.z = ldf_agent(hb + 2);
            hv.w = ldf_agent(hb + 3);
            *(float4*)(hl + tid * 4) = hv;
            __syncthreads();
        }
    }
}

// ---------------- column sum of S -> SSUM ----------------
__global__ void __launch_bounds__(256) k_colsum(const float* __restrict__ S, float* __restrict__ out)
{
    const int j = blockIdx.x * 256 + threadIdx.x;
    float a = 0.f;
    for (int t = 0; t < PSEQ; ++t) a += S[(size_t)t * NH2 + j];
    out[j] = a;
}

// ---------------- matvec: vout[r] = W[r]·vin + bscale*b[r] ----------------
__global__ void __launch_bounds__(256) k_mv(
    const float* __restrict__ W, const float* __restrict__ b, float bscale,
    const float* __restrict__ vin, float* __restrict__ vout)
{
    __shared__ float v[NH2];
    for (int i = threadIdx.x; i < NH2; i += 256) v[i] = vin[i];
    __syncthreads();
    const int r = blockIdx.x * 256 + threadIdx.x;
    const float4* wr = (const float4*)(W + (size_t)r * NH2);
    float a0 = 0, a1 = 0, a2 = 0, a3 = 0;
    for (int k4 = 0; k4 < NH2 / 4; ++k4) {
        float4 w4 = wr[k4];
        float4 x4 = *(const float4*)(&v[k4 * 4]);
        a0 = fmaf(w4.x, x4.x, a0); a1 = fmaf(w4.y, x4.y, a1);
        a2 = fmaf(w4.z, x4.z, a2); a3 = fmaf(w4.w, x4.w, a3);
    }
    vout[r] = (a0 + a1) + (a2 + a3) + bscale * b[r];
}

extern "C" void kernel_launch(void* const* d_in, const int* in_sizes, int n_in,
                              void* d_out, int out_size, void* d_ws, size_t ws_size,
                              hipStream_t stream)
{
    const float* sent   = (const float*)d_in[0];
    const float* action = (const float*)d_in[1];
    const int*   apos   = (const int*)  d_in[2];
    const float* Wih1   = (const float*)d_in[3];
    const float* Whh1   = (const float*)d_in[4];
    const float* bih1   = (const float*)d_in[5];
    const float* bhh1   = (const float*)d_in[6];
    const float* W1     = (const float*)d_in[7];
    const float* b1     = (const float*)d_in[8];
    const float* Wih2   = (const float*)d_in[9];
    const float* Whh2   = (const float*)d_in[10];
    const float* bih2   = (const float*)d_in[11];
    const float* bhh2   = (const float*)d_in[12];
    const float* W2     = (const float*)d_in[13];
    const float* b2     = (const float*)d_in[14];
    const float* ipw    = (const float*)d_in[15];
    const float* ipb    = (const float*)d_in[16];
    const float* opw    = (const float*)d_in[17];
    const float* opb    = (const float*)d_in[18];

    char* ws = (char*)d_ws;
    float*          X1   = (float*)(ws + OFF_X1);
    unsigned short* HBF  = (unsigned short*)(ws + OFF_HBF);
    float*          EMB  = (float*)(ws + OFF_EMB);
    float*          EMB2 = (float*)(ws + OFF_EMB2);
    float*          X2   = (float*)(ws + OFF_X2);
    float*          PH   = (float*)(ws + OFF_PH);
    float*          S    = (float*)(ws + OFF_S);
    float*          H2   = (float*)(ws + OFF_H2);
    float*          SSUM = (float*)(ws + OFF_SSUM);
    float*          TMP  = (float*)(ws + OFF_TMP);
    int*            META = (int*)  (ws + OFF_META);
    int*            SYNC = (int*)  (ws + OFF_SYNC);

    // re-zero stateful buffers every call (graph replays)
    hipMemsetAsync(ws + OFF_HBF, 0, SZ_HBF, stream);
    hipMemsetAsync(ws + OFF_SYNC, 0, SZ_SYNC, stream);

    hipFuncSetAttribute((const void*)k_s1, hipFuncAttributeMaxDynamicSharedMemorySize, S1_LDS);

    // X1 = sent @ Wih1.T + bih1 + bhh1   (2048 x 2400, K=300)
    gemm_rows<32><<<dim3(10, 64), 256, 0, stream>>>(sent, TSEQ, DIN, Wih1, 4 * NH1, bih1, bhh1, X1, 0);
    // segment starts / lengths / sort
    k_start<<<1, 256, 0, stream>>>(action, apos, META);
    // stage-1 chains (MFMA) -> EMB
    k_s1<<<75, 512, S1_LDS, stream>>>(X1, Whh1, META, HBF, EMB, SYNC);
    // EMB2 = tanh(EMB @ W1.T + b1)       (256 x 600, K=600)
    gemm_rows<8><<<dim3(3, 32), 256, 0, stream>>>(EMB, PSEQ, NH1, W1, NH1, b1, nullptr, EMB2, 1);
    // X2 = EMB2 @ Wih2.T + bih2 + bhh2   (256 x 8192, K=600)
    gemm_rows<32><<<dim3(32, 8), 256, 0, stream>>>(EMB2, PSEQ, NH1, Wih2, 4 * NH2, bih2, bhh2, X2, 0);
    // stage-2 LSTM -> PH (256 x 2048)
    k_s2<<<256, 512, 0, stream>>>(X2, Whh2, H2, PH, SYNC);
    // S = tanh(PH @ W2.T + b2)           (256 x 2048, K=2048)
    gemm_rows<8><<<dim3(8, 32), 256, 0, stream>>>(PH, PSEQ, NH2, W2, NH2, b2, nullptr, S, 1);
    // SSUM = column sums of S
    k_colsum<<<8, 256, 0, stream>>>(S, SSUM);
    // attention collapse: out = (SSUM @ Wv.T + 256*bv) @ Wo.T + 256*bo
    k_mv<<<8, 256, 0, stream>>>(ipw + (size_t)4096 * NH2, ipb + 4096, 256.f, SSUM, TMP);
    k_mv<<<8, 256, 0, stream>>>(opw, opb, 256.f, TMP, (float*)d_out);
}

// Round 7
// 2243.013 us; speedup vs baseline: 2.3318x; 1.0002x over previous
//
#include <hip/hip_runtime.h>
#include <cstdint>
#include <cstddef>

// ---------------- problem constants ----------------
static constexpr int TSEQ = 2048;   // T
static constexpr int PSEQ = 256;    // P
static constexpr int DIN  = 300;
static constexpr int NH1  = 600;
static constexpr int NH2  = 2048;

// ---------------- ws layout (bytes) ----------------
static constexpr size_t OFF_X1   = 0;                                   // [2048][2400] f32
static constexpr size_t SZ_X1    = (size_t)TSEQ * 4 * NH1 * 4;
static constexpr size_t OFF_HBF  = OFF_X1 + SZ_X1;                      // [2][256][600] bf16 dbl-buf
static constexpr size_t SZ_HBF   = 2ull * PSEQ * NH1 * 2;
static constexpr size_t OFF_EMB  = OFF_HBF + SZ_HBF;                    // [256][600] f32
static constexpr size_t SZ_EMB   = (size_t)PSEQ * NH1 * 4;
static constexpr size_t OFF_EMB2 = OFF_EMB + SZ_EMB;                    // [256][600] f32
static constexpr size_t SZ_EMB2  = (size_t)PSEQ * NH1 * 4;
static constexpr size_t OFF_X2   = OFF_EMB2 + SZ_EMB2;                  // [256][8192] f32
static constexpr size_t SZ_X2    = (size_t)PSEQ * 4 * NH2 * 4;
static constexpr size_t OFF_PH   = OFF_X2 + SZ_X2;                      // [256][2048] f32
static constexpr size_t SZ_PH    = (size_t)PSEQ * NH2 * 4;
static constexpr size_t OFF_S    = OFF_PH + SZ_PH;                      // [256][2048] f32
static constexpr size_t SZ_S     = (size_t)PSEQ * NH2 * 4;
static constexpr size_t OFF_H2   = OFF_S + SZ_S;                        // [2][2048] f32
static constexpr size_t SZ_H2    = 2ull * NH2 * 4;
static constexpr size_t OFF_SSUM = OFF_H2 + SZ_H2;                      // 2048 f32
static constexpr size_t OFF_TMP  = OFF_SSUM + 8192;                     // 2048 f32
static constexpr size_t OFF_META = OFF_TMP + 8192;                      // ints: st[256] L[256] ord[256] Ls[256] lmax
static constexpr size_t OFF_SYNC = OFF_META + 8192;                     // barrier counters (2 regions x 2048 ints)
static constexpr size_t SZ_SYNC  = 16384;

// k_s1 dynamic LDS: W 32x600 bf16 + h 64x600 bf16 + g 32x68 f32 + c 256x8 f32 + meta 3x256 int
static constexpr int S1_LDS = (32*600 + 64*600) * 2 + 32*68*4 + 256*8*4 + 3*256*4;   // 135168

#define DEVI __device__ __forceinline__

typedef __attribute__((ext_vector_type(8))) short short8v;   // 8 bf16 (4 VGPRs)
typedef __attribute__((ext_vector_type(4))) float f32x4;     // MFMA acc

DEVI float sigm(float x) {
    x = fminf(30.f, fmaxf(-30.f, x));
    return 1.f / (1.f + __expf(-x));
}
DEVI float tanh_f(float x) {
    x = fminf(15.f, fmaxf(-15.f, x));
    float t = __expf(2.f * x);
    return (t - 1.f) / (t + 1.f);
}
DEVI uint16_t f2bf(float f) {  // RNE fp32->bf16
    uint32_t u = __float_as_uint(f);
    return (uint16_t)((u + 0x7fffu + ((u >> 16) & 1u)) >> 16);
}

DEVI int ld_agent(const int* p) {
    return __hip_atomic_load(p, __ATOMIC_RELAXED, __HIP_MEMORY_SCOPE_AGENT);
}
DEVI unsigned int ldu_agent(const unsigned int* p) {
    return __hip_atomic_load(p, __ATOMIC_RELAXED, __HIP_MEMORY_SCOPE_AGENT);
}
DEVI float ldf_agent(const float* p) {
    return __hip_atomic_load(p, __ATOMIC_RELAXED, __HIP_MEMORY_SCOPE_AGENT);
}
DEVI void stu_agent(unsigned int* p, unsigned int v) {
    __hip_atomic_store(p, v, __ATOMIC_RELAXED, __HIP_MEMORY_SCOPE_AGENT);
}
DEVI void stf_agent(float* p, float v) {
    __hip_atomic_store(p, v, __ATOMIC_RELAXED, __HIP_MEMORY_SCOPE_AGENT);
}

// ---- fence-free device barrier: relaxed atomics only; data moves via sc-flagged ops ----
// Correctness: writers' sc-stores drained by the __syncthreads (per-wave vmcnt(0)) BEFORE
// the arrive-RMW; arrive -> root -> go all execute at the device coherence point; readers'
// sc-loads also read the coherence point. No buffer_wbl2 / buffer_inv anywhere.
// area ints: arrive[b] @ b*32 ; root @ 600 ; go[b] @ 1024 + b*32.
DEVI void barrier3(int* area, int wgid, int nb, int pb, int phase) {
    __syncthreads();   // all waves' outstanding global (sc) stores retired
    if (threadIdx.x == 0) {
        const int b = wgid % nb;
        int old = __hip_atomic_fetch_add(&area[b * 32], 1,
                                         __ATOMIC_RELAXED, __HIP_MEMORY_SCOPE_AGENT);
        if ((old % pb) == pb - 1) {
            int old2 = __hip_atomic_fetch_add(&area[600], 1,
                                              __ATOMIC_RELAXED, __HIP_MEMORY_SCOPE_AGENT);
            if ((old2 % nb) == nb - 1) {           // last arriver overall -> releaser
                for (int i = 0; i < nb; ++i)
                    stu_agent((unsigned int*)&area[1024 + i * 32], (unsigned int)(phase + 1));
            }
        }
        while (ld_agent(&area[1024 + b * 32]) < phase + 1)
            __builtin_amdgcn_s_sleep(1);
    }
    __syncthreads();
}

// ---------------- generic fp32 GEMM: out[t][r] = act(X[t]·W[r] + bA[r] (+ bB[r])) ----------------
template <int TBLK>
__global__ void __launch_bounds__(256) gemm_rows(
    const float* __restrict__ X, int T, int K,
    const float* __restrict__ W, int R,
    const float* __restrict__ bA, const float* __restrict__ bB,
    float* __restrict__ out, int act)
{
    __shared__ float xt[TBLK][448];
    const int r  = blockIdx.x * 256 + threadIdx.x;
    const int t0 = blockIdx.y * TBLK;
    float acc[TBLK];
#pragma unroll
    for (int i = 0; i < TBLK; ++i) acc[i] = 0.f;

    for (int kc0 = 0; kc0 < K; kc0 += 448) {
        const int kc  = (K - kc0 < 448) ? (K - kc0) : 448;
        const int kc4 = kc >> 2;
        __syncthreads();
        for (int idx = threadIdx.x; idx < TBLK * kc4; idx += 256) {
            int tt = idx / kc4, kk = idx - tt * kc4;
            float4 v = make_float4(0.f, 0.f, 0.f, 0.f);
            if (t0 + tt < T)
                v = *(const float4*)(X + (size_t)(t0 + tt) * K + kc0 + kk * 4);
            *(float4*)(&xt[tt][kk * 4]) = v;
        }
        __syncthreads();
        if (r < R) {
            const float4* wr = (const float4*)(W + (size_t)r * K + kc0);
            for (int k4 = 0; k4 < kc4; ++k4) {
                float4 w4 = wr[k4];
#pragma unroll
                for (int tt = 0; tt < TBLK; ++tt) {
                    float4 x4 = *(const float4*)(&xt[tt][k4 * 4]);
                    acc[tt] = fmaf(w4.x, x4.x, acc[tt]);
                    acc[tt] = fmaf(w4.y, x4.y, acc[tt]);
                    acc[tt] = fmaf(w4.z, x4.z, acc[tt]);
                    acc[tt] = fmaf(w4.w, x4.w, acc[tt]);
                }
            }
        }
    }
    if (r < R) {
        float bb = bA[r] + (bB ? bB[r] : 0.f);
#pragma unroll
        for (int tt = 0; tt < TBLK; ++tt) {
            if (t0 + tt < T) {
                float v = acc[tt] + bb;
                if (act) v = tanh_f(v);
                out[(size_t)(t0 + tt) * R + r] = v;
            }
        }
    }
}

// ---------------- segment starts + length-sort (1 block, 256 threads) ----------------
__global__ void __launch_bounds__(256) k_start(
    const float* __restrict__ action, const int* __restrict__ apos, int* __restrict__ meta)
{
    __shared__ int Lsh[256];
    const int p = threadIdx.x;
    const int pos = apos[p];
    int u = pos;
    while (u > 0 && action[u - 1] == 0.0f) --u;
    const int L = pos - u + 1;
    meta[p] = u;
    meta[256 + p] = L;
    Lsh[p] = L;
    __syncthreads();
    int rank = 0;
    for (int q = 0; q < 256; ++q) {
        int Lq = Lsh[q];
        if (Lq > L || (Lq == L && q < p)) ++rank;
    }
    meta[512 + rank] = p;
    meta[768 + rank] = L;
    if (rank == 0) meta[1024] = L;
}

// ---------------- stage-1 LSTM via MFMA: 75 wgs x 8 units, chains lockstep ----------------
__global__ void __launch_bounds__(512) k_s1(
    const float* __restrict__ X1, const float* __restrict__ Whh1,
    const int* __restrict__ meta,
    unsigned short* __restrict__ Hbf, float* __restrict__ EMB,
    int* __restrict__ sync)
{
    extern __shared__ char smem[];
    unsigned short* wl = (unsigned short*)smem;            // [32][600] bf16
    unsigned short* hl = wl + 32 * 600;                    // [64][600] bf16
    float* glds = (float*)(hl + 64 * 600);                 // [32][68] gates
    float* clds = glds + 32 * 68;                          // [256][8] c-state
    int* ordC  = (int*)(clds + 256 * 8);
    int* ordST = ordC + 256;
    int* ordL  = ordST + 256;

    const int wg  = blockIdx.x;        // 0..74, owns units u0..u0+7
    const int u0  = wg * 8;
    const int tid = threadIdx.x;
    const int lane = tid & 63;
    const int w  = tid >> 6;
    const int ct = w & 3, rt = w >> 2;

    for (int idx = tid; idx < 32 * 150; idx += 512) {
        int rr = idx / 150, j = idx - rr * 150;
        int gamma = rr >> 3, u = rr & 7;
        float4 v = *(const float4*)(Whh1 + (size_t)(gamma * 600 + u0 + u) * 600 + j * 4);
        ushort4 pk = make_ushort4(f2bf(v.x), f2bf(v.y), f2bf(v.z), f2bf(v.w));
        *(ushort4*)(wl + rr * 600 + j * 4) = pk;
    }
    if (tid < 256) {
        int p = meta[512 + tid];
        ordC[tid]  = p;
        ordST[tid] = meta[p];
        ordL[tid]  = meta[256 + p];
    }
    for (int idx = tid; idx < 2048; idx += 512) clds[idx] = 0.f;
    __syncthreads();

    const int lmax = ordL[0];
    int A = 256;

    for (int k = 0; k < lmax; ++k) {
        while (A > 0 && ordL[A - 1] <= k) --A;
        const int rb = k & 1;
        const unsigned short* Hr = Hbf + (size_t)rb * PSEQ * NH1;
        unsigned short*       Hw = Hbf + (size_t)(rb ^ 1) * PSEQ * NH1;
        const int ng = (A + 63) >> 6;

        for (int g = 0; g < ng; ++g) {
            const int sc  = (A - g * 64 < 64) ? (A - g * 64) : 64;
            const int nst = (sc + 15) & ~15;
            __syncthreads();
            // stage h (bf16) via coherent uint loads (2 bf16 per load)
            for (int idx = tid; idx < nst * 300; idx += 512) {
                int ci = idx / 300, j2 = idx - ci * 300;
                int ch = ordC[g * 64 + ci];
                unsigned int v = ldu_agent((const unsigned int*)(Hr + (size_t)ch * 600) + j2);
                *((unsigned int*)(hl + (size_t)ci * 600) + j2) = v;
            }
            __syncthreads();

            // epilogue-role prefetch: X1 gate values + meta (independent of h)
            const int s_loc = tid >> 3, eu = tid & 7;
            const bool ep = (s_loc < sc);
            int ch = 0, st = 0, L = 0;
            float xv0 = 0, xv1 = 0, xv2 = 0, xv3 = 0;
            if (ep) {
                ch = ordC[g * 64 + s_loc];
                st = ordST[g * 64 + s_loc];
                L  = ordL[g * 64 + s_loc];
                const float* xr = X1 + (size_t)(st + k) * 2400 + u0 + eu;
                xv0 = xr[0]; xv1 = xr[600]; xv2 = xr[1200]; xv3 = xr[1800];
            }

            // MFMA: D[chain][row] += h · W^T
            if (ct * 16 < sc) {
                f32x4 acc = {0.f, 0.f, 0.f, 0.f};
                const int kg = lane >> 4;
                const short* ha = (const short*)hl + (ct * 16 + (lane & 15)) * 600;
                const short* wb = (const short*)wl + (rt * 16 + (lane & 15)) * 600;
#pragma unroll
                for (int kt = 0; kt < 19; ++kt) {
                    int k0 = kt * 32 + kg * 8;
                    short8v af = {0, 0, 0, 0, 0, 0, 0, 0};
                    short8v bf = {0, 0, 0, 0, 0, 0, 0, 0};
                    if (k0 < 600) {
                        af = *(const short8v*)(ha + k0);
                        bf = *(const short8v*)(wb + k0);
                    }
                    acc = __builtin_amdgcn_mfma_f32_16x16x32_bf16(af, bf, acc, 0, 0, 0);
                }
                const int brow = rt * 16 + (lane & 15);
                const int ch0  = ct * 16 + ((lane >> 4) << 2);
                *(f32x4*)(glds + brow * 68 + ch0) = acc;
            }
            __syncthreads();

            // gate epilogue: compute unconditionally (safe garbage), guard stores with ep
            {
                float gi = glds[(0 * 8 + eu) * 68 + s_loc] + xv0;
                float gf = glds[(1 * 8 + eu) * 68 + s_loc] + xv1;
                float gg = glds[(2 * 8 + eu) * 68 + s_loc] + xv2;
                float go = glds[(3 * 8 + eu) * 68 + s_loc] + xv3;
                float co = clds[ch * 8 + eu];
                float cn = sigm(gf) * co + sigm(gi) * tanh_f(gg);
                float hn = sigm(go) * tanh_f(cn);
                if (ep) clds[ch * 8 + eu] = cn;
                unsigned int pk = (unsigned int)f2bf(hn);
                unsigned int hi = __shfl_down(pk, 1, 64);
                if (ep && (eu & 1) == 0)
                    stu_agent((unsigned int*)(Hw + (size_t)ch * 600 + u0 + eu), pk | (hi << 16));
                if (ep && k == L - 1)
                    EMB[(size_t)ch * 600 + u0 + eu] = hn;
            }
        }
        if (k < lmax - 1) barrier3(sync, wg, 15, 5, k);   // 75 = 15 buckets x 5
    }
}

// ---------------- stage-2 LSTM: 256 wgs x 8 units; 512 thr; wave w owns unit w ----------------
__global__ void __launch_bounds__(512) k_s2(
    const float* __restrict__ X2, const float* __restrict__ Whh2,
    float* __restrict__ h2, float* __restrict__ PH, int* __restrict__ sync)
{
    __shared__ float hl[NH2];
    const int wg   = blockIdx.x;
    const int tid  = threadIdx.x;
    const int lane = tid & 63;
    const int w    = tid >> 6;         // wave = unit 0..7
    const int uu   = wg * 8 + w;
    int* syncg = sync + 2048;

    // preload 4 gate rows fp32 into VGPRs: wv[g][j*4+c] = Whh2[g*2048+uu][j*256+lane*4+c]
    float wv[4][32];
#pragma unroll
    for (int g = 0; g < 4; ++g) {
        const float* rp = Whh2 + ((size_t)(g * NH2 + uu)) * NH2 + lane * 4;
#pragma unroll
        for (int j = 0; j < 8; ++j) {
            float4 a = *(const float4*)(rp + j * 256);
            wv[g][j * 4 + 0] = a.x; wv[g][j * 4 + 1] = a.y;
            wv[g][j * 4 + 2] = a.z; wv[g][j * 4 + 3] = a.w;
        }
    }
    *(float4*)(hl + tid * 4) = make_float4(0.f, 0.f, 0.f, 0.f);
    float creg = 0.f;
    __syncthreads();

    for (int t = 0; t < PSEQ; ++t) {
        // prefetch x gate values (lane0 of each wave), independent of h
        float x0 = 0, x1 = 0, x2 = 0, x3 = 0;
        if (lane == 0) {
            const float* xr = X2 + (size_t)t * (4 * NH2) + uu;
            x0 = xr[0]; x1 = xr[NH2]; x2 = xr[2 * NH2]; x3 = xr[3 * NH2];
        }
        float a0 = 0, a1 = 0, a2 = 0, a3 = 0;
#pragma unroll
        for (int j = 0; j < 8; ++j) {
            float4 hv = *(const float4*)(hl + j * 256 + lane * 4);
            a0 = fmaf(wv[0][j*4+0], hv.x, a0); a0 = fmaf(wv[0][j*4+1], hv.y, a0);
            a0 = fmaf(wv[0][j*4+2], hv.z, a0); a0 = fmaf(wv[0][j*4+3], hv.w, a0);
            a1 = fmaf(wv[1][j*4+0], hv.x, a1); a1 = fmaf(wv[1][j*4+1], hv.y, a1);
            a1 = fmaf(wv[1][j*4+2], hv.z, a1); a1 = fmaf(wv[1][j*4+3], hv.w, a1);
            a2 = fmaf(wv[2][j*4+0], hv.x, a2); a2 = fmaf(wv[2][j*4+1], hv.y, a2);
            a2 = fmaf(wv[2][j*4+2], hv.z, a2); a2 = fmaf(wv[2][j*4+3], hv.w, a2);
            a3 = fmaf(wv[3][j*4+0], hv.x, a3); a3 = fmaf(wv[3][j*4+1], hv.y, a3);
            a3 = fmaf(wv[3][j*4+2], hv.z, a3); a3 = fmaf(wv[3][j*4+3], hv.w, a3);
        }
#pragma unroll
        for (int m = 32; m > 0; m >>= 1) {
            a0 += __shfl_xor(a0, m, 64); a1 += __shfl_xor(a1, m, 64);
            a2 += __shfl_xor(a2, m, 64); a3 += __shfl_xor(a3, m, 64);
        }
        if (lane == 0) {
            float gi = a0 + x0, gf = a1 + x1, gg = a2 + x2, go = a3 + x3;
            float cn = sigm(gf) * creg + sigm(gi) * tanh_f(gg);
            float hn = sigm(go) * tanh_f(cn);
            creg = cn;
            stf_agent(h2 + ((t + 1) & 1) * NH2 + uu, hn);   // coherent write-through
            PH[(size_t)t * NH2 + uu] = hn;
        }
        if (t < PSEQ - 1) {
            barrier3(syncg, wg, 16, 16, t);   // 256 = 16 x 16
            // stage next h: 4 coherent dword loads per thread -> LDS
            const float* hb = h2 + ((t + 1) & 1) * NH2 + tid * 4;
            float4 hv;
            hv.x = ldf_agent(hb + 0);
            hv.y = ldf_agent(hb + 1);
            hv.z = ldf_agent(hb + 2);
            hv.w = ldf_agent(hb + 3);
            *(float4*)(hl + tid * 4) = hv;
            __syncthreads();
        }
    }
}

// ---------------- column sum of S -> SSUM ----------------
__global__ void __launch_bounds__(256) k_colsum(const float* __restrict__ S, float* __restrict__ out)
{
    const int j = blockIdx.x * 256 + threadIdx.x;
    float a = 0.f;
    for (int t = 0; t < PSEQ; ++t) a += S[(size_t)t * NH2 + j];
    out[j] = a;
}

// ---------------- matvec: vout[r] = W[r]·vin + bscale*b[r] ----------------
__global__ void __launch_bounds__(256) k_mv(
    const float* __restrict__ W, const float* __restrict__ b, float bscale,
    const float* __restrict__ vin, float* __restrict__ vout)
{
    __shared__ float v[NH2];
    for (int i = threadIdx.x; i < NH2; i += 256) v[i] = vin[i];
    __syncthreads();
    const int r = blockIdx.x * 256 + threadIdx.x;
    const float4* wr = (const float4*)(W + (size_t)r * NH2);
    float a0 = 0, a1 = 0, a2 = 0, a3 = 0;
    for (int k4 = 0; k4 < NH2 / 4; ++k4) {
        float4 w4 = wr[k4];
        float4 x4 = *(const float4*)(&v[k4 * 4]);
        a0 = fmaf(w4.x, x4.x, a0); a1 = fmaf(w4.y, x4.y, a1);
        a2 = fmaf(w4.z, x4.z, a2); a3 = fmaf(w4.w, x4.w, a3);
    }
    vout[r] = (a0 + a1) + (a2 + a3) + bscale * b[r];
}

extern "C" void kernel_launch(void* const* d_in, const int* in_sizes, int n_in,
                              void* d_out, int out_size, void* d_ws, size_t ws_size,
                              hipStream_t stream)
{
    const float* sent   = (const float*)d_in[0];
    const float* action = (const float*)d_in[1];
    const int*   apos   = (const int*)  d_in[2];
    const float* Wih1   = (const float*)d_in[3];
    const float* Whh1   = (const float*)d_in[4];
    const float* bih1   = (const float*)d_in[5];
    const float* bhh1   = (const float*)d_in[6];
    const float* W1     = (const float*)d_in[7];
    const float* b1     = (const float*)d_in[8];
    const float* Wih2   = (const float*)d_in[9];
    const float* Whh2   = (const float*)d_in[10];
    const float* bih2   = (const float*)d_in[11];
    const float* bhh2   = (const float*)d_in[12];
    const float* W2     = (const float*)d_in[13];
    const float* b2     = (const float*)d_in[14];
    const float* ipw    = (const float*)d_in[15];
    const float* ipb    = (const float*)d_in[16];
    const float* opw    = (const float*)d_in[17];
    const float* opb    = (const float*)d_in[18];

    char* ws = (char*)d_ws;
    float*          X1   = (float*)(ws + OFF_X1);
    unsigned short* HBF  = (unsigned short*)(ws + OFF_HBF);
    float*          EMB  = (float*)(ws + OFF_EMB);
    float*          EMB2 = (float*)(ws + OFF_EMB2);
    float*          X2   = (float*)(ws + OFF_X2);
    float*          PH   = (float*)(ws + OFF_PH);
    float*          S    = (float*)(ws + OFF_S);
    float*          H2   = (float*)(ws + OFF_H2);
    float*          SSUM = (float*)(ws + OFF_SSUM);
    float*          TMP  = (float*)(ws + OFF_TMP);
    int*            META = (int*)  (ws + OFF_META);
    int*            SYNC = (int*)  (ws + OFF_SYNC);

    // re-zero stateful buffers every call (graph replays)
    hipMemsetAsync(ws + OFF_HBF, 0, SZ_HBF, stream);
    hipMemsetAsync(ws + OFF_SYNC, 0, SZ_SYNC, stream);

    hipFuncSetAttribute((const void*)k_s1, hipFuncAttributeMaxDynamicSharedMemorySize, S1_LDS);

    // X1 = sent @ Wih1.T + bih1 + bhh1   (2048 x 2400, K=300)
    gemm_rows<32><<<dim3(10, 64), 256, 0, stream>>>(sent, TSEQ, DIN, Wih1, 4 * NH1, bih1, bhh1, X1, 0);
    // segment starts / lengths / sort
    k_start<<<1, 256, 0, stream>>>(action, apos, META);
    // stage-1 chains (MFMA) -> EMB
    k_s1<<<75, 512, S1_LDS, stream>>>(X1, Whh1, META, HBF, EMB, SYNC);
    // EMB2 = tanh(EMB @ W1.T + b1)       (256 x 600, K=600)
    gemm_rows<8><<<dim3(3, 32), 256, 0, stream>>>(EMB, PSEQ, NH1, W1, NH1, b1, nullptr, EMB2, 1);
    // X2 = EMB2 @ Wih2.T + bih2 + bhh2   (256 x 8192, K=600)
    gemm_rows<32><<<dim3(32, 8), 256, 0, stream>>>(EMB2, PSEQ, NH1, Wih2, 4 * NH2, bih2, bhh2, X2, 0);
    // stage-2 LSTM -> PH (256 x 2048)
    k_s2<<<256, 512, 0, stream>>>(X2, Whh2, H2, PH, SYNC);
    // S = tanh(PH @ W2.T + b2)           (256 x 2048, K=2048)
    gemm_rows<8><<<dim3(8, 32), 256, 0, stream>>>(PH, PSEQ, NH2, W2, NH2, b2, nullptr, S, 1);
    // SSUM = column sums of S
    k_colsum<<<8, 256, 0, stream>>>(S, SSUM);
    // attention collapse: out = (SSUM @ Wv.T + 256*bv) @ Wo.T + 256*bo
    k_mv<<<8, 256, 0, stream>>>(ipw + (size_t)4096 * NH2, ipb + 4096, 256.f, SSUM, TMP);
    k_mv<<<8, 256, 0, stream>>>(opw, opb, 256.f, TMP, (float*)d_out);
}